// Round 7
// baseline (310.535 us; speedup 1.0000x reference)
//
#include <hip/hip_runtime.h>
#include <hip/hip_bf16.h>
#include <math.h>

// ---------------------------------------------------------------------------
// 2-layer GAT on MI355X.
// R6: agg kernels compute softmax numerators inline with zero redundancy
// (cooperative per-wave exp2 + ds_bpermute broadcast) -> k_score1/2, p1/p2,
// dstid all eliminated. Gather rows loaded 32-lane wide (uint2/uint), two
// edges per wave, halves combined via shfl_xor(32). CSR via bucket sort.
// GEMMs via bf16 MFMA 16x16x32.
// ---------------------------------------------------------------------------

typedef __attribute__((ext_vector_type(8))) short short8;
typedef __attribute__((ext_vector_type(4))) float f32x4;

__device__ __forceinline__ float bflo(uint u) { return __uint_as_float(u << 16); }
__device__ __forceinline__ float bfhi(uint u) { return __uint_as_float(u & 0xffff0000u); }
__device__ __forceinline__ ushort f2bf(float f) {  // RNE f32->bf16
    uint u = __float_as_uint(f);
    u += 0x7fff + ((u >> 16) & 1);
    return (ushort)(u >> 16);
}
#define LOG2E 1.44269504088896f

// ----------------------------- CSR build ----------------------------------
#define CSR_CAP 4096

__global__ __launch_bounds__(256) void k_bhist(const int* __restrict__ dst, int e,
                                               int* __restrict__ bcount) {
    __shared__ int h[1024];
    int t = threadIdx.x;
    for (int i = t; i < 1024; i += 256) h[i] = 0;
    __syncthreads();
    int c0 = blockIdx.x * 4096, c1 = min(c0 + 4096, e);
    for (int i = c0 + t; i < c1; i += 256) atomicAdd(&h[dst[i] >> 7], 1);
    __syncthreads();
    for (int i = t; i < 1024; i += 256)
        if (h[i]) atomicAdd(&bcount[i], h[i]);
}

__global__ __launch_bounds__(256) void k_bscan(const int* __restrict__ bcount, int nb, int n,
                                               int* __restrict__ ebase, int* __restrict__ ecur,
                                               int* __restrict__ cbase) {
    __shared__ int ae[1024], be[1024], ac[1024], bc[1024];
    int t = threadIdx.x;
    for (int i = t; i < 1024; i += 256) {
        int v = 0, nn = 0;
        if (i < nb) {
            v = bcount[i];
            nn = min(128, n - (i << 7));
        }
        ae[i] = v;
        ac[i] = v + nn;
    }
    __syncthreads();
    int* pa = ae; int* qa = be; int* pc = ac; int* qc = bc;
    for (int off = 1; off < 1024; off <<= 1) {
        for (int i = t; i < 1024; i += 256) {
            int va = pa[i], vc = pc[i];
            if (i >= off) { va += pa[i - off]; vc += pc[i - off]; }
            qa[i] = va; qc[i] = vc;
        }
        __syncthreads();
        int* tm = pa; pa = qa; qa = tm;
        tm = pc; pc = qc; qc = tm;
    }
    for (int i = t; i < 1024; i += 256) {
        if (i < nb) {
            int ea = (i == 0) ? 0 : pa[i - 1];
            int ca = (i == 0) ? 0 : pc[i - 1];
            ebase[i] = ea; ecur[i] = ea; cbase[i] = ca;
        }
    }
}

// entry packed as (src << 7) | (dst & 127)
__global__ __launch_bounds__(256) void k_part(const int* __restrict__ src,
                                              const int* __restrict__ dst, int e,
                                              int* __restrict__ ecur, int* __restrict__ ebuf) {
    __shared__ int h[1024];
    __shared__ int base[1024];
    int t = threadIdx.x;
    int c0 = blockIdx.x * 4096, c1 = min(c0 + 4096, e);
    for (int i = t; i < 1024; i += 256) h[i] = 0;
    __syncthreads();
    for (int i = c0 + t; i < c1; i += 256) atomicAdd(&h[dst[i] >> 7], 1);
    __syncthreads();
    for (int i = t; i < 1024; i += 256) {
        int c = h[i];
        base[i] = c ? atomicAdd(&ecur[i], c) : 0;
        h[i] = 0;
    }
    __syncthreads();
    for (int i = c0 + t; i < c1; i += 256) {
        int d = dst[i], b = d >> 7;
        int r = atomicAdd(&h[b], 1);
        ebuf[base[b] + r] = (src[i] << 7) | (d & 127);
    }
}

__global__ __launch_bounds__(256) void k_build(const int* __restrict__ ebuf,
                                               const int* __restrict__ bcount,
                                               const int* __restrict__ ebase,
                                               const int* __restrict__ cbase,
                                               int* __restrict__ rowptr,
                                               int* __restrict__ csr, int n, int nb) {
    __shared__ int cnt[128];
    __shared__ int sc[128], sc2[128];
    __shared__ int csr_l[CSR_CAP];
    int b = blockIdx.x, t = threadIdx.x;
    int n0 = b << 7;
    int nn = min(128, n - n0);
    int ec = bcount[b], eb = ebase[b], cb = cbase[b];
    if (t < 128) cnt[t] = 0;
    __syncthreads();
    for (int i = t; i < ec; i += 256) atomicAdd(&cnt[ebuf[eb + i] & 127], 1);
    __syncthreads();
    if (t < 128) sc[t] = (t < nn) ? cnt[t] + 1 : 0;
    __syncthreads();
    int* p = sc; int* q = sc2;
    for (int off = 1; off < 128; off <<= 1) {
        if (t < 128) {
            int v = p[t];
            if (t >= off) v += p[t - off];
            q[t] = v;
        }
        __syncthreads();
        int* tm = p; p = q; q = tm;
    }
    int total = p[127];  // == ec + nn
    if (total <= CSR_CAP) {
        if (t < nn) {
            int off = (t == 0) ? 0 : p[t - 1];
            rowptr[n0 + t] = cb + off;
            csr_l[off] = n0 + t;   // self-loop
            cnt[t] = off + 1;
        }
        __syncthreads();
        for (int i = t; i < ec; i += 256) {
            int v = ebuf[eb + i];
            int s = atomicAdd(&cnt[v & 127], 1);
            csr_l[s] = v >> 7;
        }
        __syncthreads();
        for (int i = t; i < total; i += 256) csr[cb + i] = csr_l[i];
    } else {  // fallback (never taken for random graphs)
        if (t < nn) {
            int off = (t == 0) ? 0 : p[t - 1];
            rowptr[n0 + t] = cb + off;
            csr[cb + off] = n0 + t;
            cnt[t] = off + 1;
        }
        __syncthreads();
        for (int i = t; i < ec; i += 256) {
            int v = ebuf[eb + i];
            int s = atomicAdd(&cnt[v & 127], 1);
            csr[cb + s] = v >> 7;
        }
    }
    if (b == nb - 1 && t == 0) rowptr[n] = cb + total;
}

// --------------------------- MFMA GEMM -------------------------------------
template <int COLS, bool XBF16>
__global__ __launch_bounds__(256) void k_gemm_mfma(const void* __restrict__ Xv,
                                                   const float* __restrict__ W,
                                                   ushort* __restrict__ Y, int n) {
    __shared__ ushort As[128][136];
    __shared__ ushort Ws[COLS][136];   // W^T: [col][k]
    const int t = threadIdx.x;
    const int row0 = blockIdx.x * 128;
    if constexpr (!XBF16) {
        const float* X = (const float*)Xv;
#pragma unroll
        for (int q = 0; q < 16; q++) {
            int idx = t + q * 256;
            int r = idx >> 5, c4 = (idx & 31) * 4;
            float4 xv = make_float4(0.f, 0.f, 0.f, 0.f);
            if (row0 + r < n) xv = *reinterpret_cast<const float4*>(&X[(size_t)(row0 + r) * 128 + c4]);
            ushort4 w4 = make_ushort4(f2bf(xv.x), f2bf(xv.y), f2bf(xv.z), f2bf(xv.w));
            *reinterpret_cast<ushort4*>(&As[r][c4]) = w4;
        }
    } else {
        const ushort* X = (const ushort*)Xv;
#pragma unroll
        for (int q = 0; q < 8; q++) {
            int idx = t + q * 256;
            int r = idx >> 4, c8 = (idx & 15) * 8;
            uint4 v = make_uint4(0u, 0u, 0u, 0u);
            if (row0 + r < n) v = *reinterpret_cast<const uint4*>(&X[(size_t)(row0 + r) * 128 + c8]);
            *reinterpret_cast<uint4*>(&As[r][c8]) = v;
        }
    }
    for (int i = t; i < 128 * COLS; i += 256) {
        int k = i / COLS, nc = i % COLS;
        Ws[nc][k] = f2bf(W[i]);
    }
    __syncthreads();
    const int w = t >> 6, l = t & 63;
    const int lr = l & 15;
    const int lk = (l >> 4) * 8;
    f32x4 acc[2][COLS / 16];
#pragma unroll
    for (int m = 0; m < 2; m++)
#pragma unroll
        for (int nb = 0; nb < COLS / 16; nb++) acc[m][nb] = (f32x4){0.f, 0.f, 0.f, 0.f};
#pragma unroll
    for (int kc = 0; kc < 128; kc += 32) {
        short8 a0 = *reinterpret_cast<const short8*>(&As[w * 32 + lr][kc + lk]);
        short8 a1 = *reinterpret_cast<const short8*>(&As[w * 32 + 16 + lr][kc + lk]);
#pragma unroll
        for (int nb = 0; nb < COLS / 16; nb++) {
            short8 bf = *reinterpret_cast<const short8*>(&Ws[nb * 16 + lr][kc + lk]);
            acc[0][nb] = __builtin_amdgcn_mfma_f32_16x16x32_bf16(a0, bf, acc[0][nb], 0, 0, 0);
            acc[1][nb] = __builtin_amdgcn_mfma_f32_16x16x32_bf16(a1, bf, acc[1][nb], 0, 0, 0);
        }
    }
#pragma unroll
    for (int m = 0; m < 2; m++)
#pragma unroll
        for (int j = 0; j < 4; j++) {
            int r = row0 + w * 32 + m * 16 + (l >> 4) * 4 + j;
            if (r < n) {
#pragma unroll
                for (int nb = 0; nb < COLS / 16; nb++)
                    Y[(size_t)r * COLS + nb * 16 + lr] = f2bf(acc[m][nb][j]);
            }
        }
}

// --------------------------- attention scores ------------------------------
// Written pre-scaled by log2(e): agg kernels use native exp2.
__global__ void k_attn1(const uint* __restrict__ hu, const float* __restrict__ a_src,
                        const float* __restrict__ a_dst, float* __restrict__ asrc,
                        float* __restrict__ adst, int n) {
    int t = blockIdx.x * 256 + threadIdx.x;
    if (t >= n * 8) return;
    int node = t >> 3, hd = t & 7;
    const uint* hp = hu + (size_t)node * 64 + hd * 8;
    float s1 = 0.f, s2 = 0.f;
#pragma unroll
    for (int q = 0; q < 8; q++) {
        uint u = hp[q];
        float v0 = bflo(u), v1 = bfhi(u);
        s1 = fmaf(v0, a_src[hd * 16 + 2 * q], s1);
        s1 = fmaf(v1, a_src[hd * 16 + 2 * q + 1], s1);
        s2 = fmaf(v0, a_dst[hd * 16 + 2 * q], s2);
        s2 = fmaf(v1, a_dst[hd * 16 + 2 * q + 1], s2);
    }
    asrc[t] = s1 * LOG2E;
    adst[t] = s2 * LOG2E;
}
__global__ void k_attn2(const uint* __restrict__ hu, const float* __restrict__ a_src,
                        const float* __restrict__ a_dst, float* __restrict__ asrc,
                        float* __restrict__ adst, int n) {
    int t = blockIdx.x * 256 + threadIdx.x;
    if (t >= n * 8) return;
    int node = t >> 3, j = t & 7;
    const uint* hp = hu + (size_t)node * 32 + j * 4;
    float s1 = 0.f, s2 = 0.f;
#pragma unroll
    for (int q = 0; q < 4; q++) {
        uint u = hp[q];
        float v0 = bflo(u), v1 = bfhi(u);
        s1 = fmaf(v0, a_src[j * 8 + 2 * q], s1);
        s1 = fmaf(v1, a_src[j * 8 + 2 * q + 1], s1);
        s2 = fmaf(v0, a_dst[j * 8 + 2 * q], s2);
        s2 = fmaf(v1, a_dst[j * 8 + 2 * q + 1], s2);
    }
#pragma unroll
    for (int o = 1; o < 8; o <<= 1) {
        s1 += __shfl_xor(s1, o);
        s2 += __shfl_xor(s2, o);
    }
    if (j == 0) { asrc[node] = s1 * LOG2E; adst[node] = s2 * LOG2E; }
}

// ------------------------ aggregation --------------------------------------
// conv1: one wave per dst; 2 edges in flight (half = lane>>5); lane owns 4
// channels (uint2 of bf16x4), head hd = cl>>2. Softmax numerators computed
// cooperatively: lane q computes p[slot 8k+(q&7)][head q>>3] for k=0..7
// (zero redundancy), consumed via ds_bpermute.
__global__ __launch_bounds__(256) void k_agg1(
    const uint* __restrict__ hu, const float* __restrict__ asrc,
    const float* __restrict__ adst, const int* __restrict__ rowptr,
    const int* __restrict__ csr, const float* __restrict__ b1,
    uint2* __restrict__ x2, int n) {
    int wid = (blockIdx.x * 256 + threadIdx.x) >> 6;
    if (wid >= n) return;
    int lane = threadIdx.x & 63;
    int half = lane >> 5, cl = lane & 31;
    int hd = cl >> 2;                      // head of my 4 channels
    int hsel = lane >> 3;                  // head this lane COMPUTES p for
    float adnm = adst[wid * 8 + hsel];
    int beg = rowptr[wid], end = rowptr[wid + 1];
    float s = 0.f, a0 = 0.f, a1 = 0.f, a2 = 0.f, a3 = 0.f;
    for (int base = beg; base < end; base += 64) {
        int cnt = min(64, end - base);
        int vidx = csr[base + min(lane, cnt - 1)];
#pragma unroll
        for (int k = 0; k < 8; k++) {
            if (k * 8 < cnt) {
                // compute p for slots [8k, 8k+8) x all heads (one per lane)
                int sP = __shfl(vidx, k * 8 + (lane & 7));
                float e = asrc[sP * 8 + hsel] + adnm;
                e = fmaxf(e, 0.2f * e);
                float Pk = exp2f(e);
#pragma unroll
                for (int j2 = 0; j2 < 4; j2++) {
                    int e2 = k * 8 + 2 * j2;           // even slot of the pair
                    if (e2 < cnt) {
                        int ee = e2 + half;
                        int eec = min(ee, cnt - 1);
                        float pe = __shfl(Pk, (eec & 7) | (hd << 3));
                        int se = __shfl(vidx, eec);
                        pe = (ee < cnt) ? pe : 0.f;
                        uint2 u = *reinterpret_cast<const uint2*>(&hu[(uint)se * 64u + 2u * cl]);
                        s += pe;
                        a0 = fmaf(pe, bflo(u.x), a0);
                        a1 = fmaf(pe, bfhi(u.x), a1);
                        a2 = fmaf(pe, bflo(u.y), a2);
                        a3 = fmaf(pe, bfhi(u.y), a3);
                    }
                }
            }
        }
    }
    s  += __shfl_xor(s, 32);
    a0 += __shfl_xor(a0, 32);
    a1 += __shfl_xor(a1, 32);
    a2 += __shfl_xor(a2, 32);
    a3 += __shfl_xor(a3, 32);
    if (half == 0) {
        float inv = 1.f / (s + 1e-16f);
        float o0 = a0 * inv + b1[4 * cl + 0];
        float o1 = a1 * inv + b1[4 * cl + 1];
        float o2 = a2 * inv + b1[4 * cl + 2];
        float o3 = a3 * inv + b1[4 * cl + 3];
        o0 = o0 > 0.f ? o0 : (__expf(o0) - 1.f);   // ELU
        o1 = o1 > 0.f ? o1 : (__expf(o1) - 1.f);
        o2 = o2 > 0.f ? o2 : (__expf(o2) - 1.f);
        o3 = o3 > 0.f ? o3 : (__expf(o3) - 1.f);
        uint2 pk;
        pk.x = (uint)f2bf(o0) | ((uint)f2bf(o1) << 16);
        pk.y = (uint)f2bf(o2) | ((uint)f2bf(o3) << 16);
        x2[(uint)wid * 32u + cl] = pk;
    }
}
// conv2: one wave per dst; 2 edges in flight; lane owns 2 channels (uint of
// bf16x2); single head -> p per slot computed by its own lane.
__global__ __launch_bounds__(256) void k_agg2(
    const uint* __restrict__ hb, const float* __restrict__ asrc,
    const float* __restrict__ adst, const int* __restrict__ rowptr,
    const int* __restrict__ csr, const float* __restrict__ b2,
    float2* __restrict__ out, int n) {
    int wid = (blockIdx.x * 256 + threadIdx.x) >> 6;
    if (wid >= n) return;
    int lane = threadIdx.x & 63;
    int half = lane >> 5, cl = lane & 31;
    float adn = adst[wid];
    int beg = rowptr[wid], end = rowptr[wid + 1];
    float s = 0.f, a0 = 0.f, a1 = 0.f;
    for (int base = beg; base < end; base += 64) {
        int cnt = min(64, end - base);
        int vidx = csr[base + min(lane, cnt - 1)];
        float e = asrc[vidx] + adn;
        e = fmaxf(e, 0.2f * e);
        float pl = exp2f(e);
#pragma unroll
        for (int jj = 0; jj < 32; jj++) {
            int e2 = 2 * jj;
            if (e2 < cnt) {
                int ee = e2 + half;
                int eec = min(ee, cnt - 1);
                float pe = __shfl(pl, eec);
                int se = __shfl(vidx, eec);
                pe = (ee < cnt) ? pe : 0.f;
                uint u = hb[(uint)se * 32u + cl];
                s += pe;
                a0 = fmaf(pe, bflo(u), a0);
                a1 = fmaf(pe, bfhi(u), a1);
            }
        }
    }
    s  += __shfl_xor(s, 32);
    a0 += __shfl_xor(a0, 32);
    a1 += __shfl_xor(a1, 32);
    if (half == 0) {
        float inv = 1.f / (s + 1e-16f);
        out[(uint)wid * 32u + cl] = make_float2(a0 * inv + b2[2 * cl],
                                                a1 * inv + b2[2 * cl + 1]);
    }
}

// ------------------------------- launch -------------------------------------
extern "C" void kernel_launch(void* const* d_in, const int* in_sizes, int n_in,
                              void* d_out, int out_size, void* d_ws, size_t ws_size,
                              hipStream_t stream) {
    const float* x   = (const float*)d_in[0];
    const int*   ei  = (const int*)d_in[1];
    const float* W1  = (const float*)d_in[2];
    const float* as1 = (const float*)d_in[3];
    const float* ad1 = (const float*)d_in[4];
    const float* b1  = (const float*)d_in[5];
    const float* W2  = (const float*)d_in[6];
    const float* as2 = (const float*)d_in[7];
    const float* ad2 = (const float*)d_in[8];
    const float* b2  = (const float*)d_in[9];
    float* out = (float*)d_out;

    int N = in_sizes[0] / 128;
    int E = in_sizes[1] / 2;
    int TOT = E + N;
    const int* src = ei;
    const int* dst = ei + E;

    char* p = (char*)d_ws;
    auto alloc = [&](size_t bytes) {
        char* r = p;
        p += (bytes + 255) & ~size_t(255);
        return r;
    };
    ushort* h1b  = (ushort*)alloc((size_t)N * 128 * 2);
    ushort* h2b  = (ushort*)alloc((size_t)N * 64 * 2);
    ushort* x2b  = (ushort*)alloc((size_t)N * 128 * 2);
    float* asrc1 = (float*)alloc((size_t)N * 8 * 4);
    float* adst1 = (float*)alloc((size_t)N * 8 * 4);
    float* asrc2 = (float*)alloc((size_t)N * 4);
    float* adst2 = (float*)alloc((size_t)N * 4);
    int* rowptr  = (int*)alloc((size_t)(N + 1) * 4);
    int* csr     = (int*)alloc((size_t)TOT * 4);
    int* ebuf    = (int*)alloc((size_t)E * 4);
    int* bcount  = (int*)alloc(1024 * 4);
    int* ebase   = (int*)alloc(1024 * 4);
    int* ecur    = (int*)alloc(1024 * 4);
    int* cbase   = (int*)alloc(1024 * 4);

    int NB = (N + 127) >> 7;
    int nbk = (E + 4095) / 4096;

    // CSR build
    hipMemsetAsync(bcount, 0, 1024 * 4, stream);
    k_bhist<<<nbk, 256, 0, stream>>>(dst, E, bcount);
    k_bscan<<<1, 256, 0, stream>>>(bcount, NB, N, ebase, ecur, cbase);
    k_part<<<nbk, 256, 0, stream>>>(src, dst, E, ecur, ebuf);
    k_build<<<NB, 256, 0, stream>>>(ebuf, bcount, ebase, cbase, rowptr, csr, N, NB);

    int gb = (N + 127) / 128;
    // conv1
    k_gemm_mfma<128, false><<<gb, 256, 0, stream>>>(x, W1, h1b, N);
    k_attn1<<<(N * 8 + 255) / 256, 256, 0, stream>>>((const uint*)h1b, as1, ad1, asrc1, adst1, N);
    k_agg1<<<(N + 3) / 4, 256, 0, stream>>>((const uint*)h1b, asrc1, adst1, rowptr, csr, b1,
                                            (uint2*)x2b, N);

    // conv2
    k_gemm_mfma<64, true><<<gb, 256, 0, stream>>>(x2b, W2, h2b, N);
    k_attn2<<<(N * 8 + 255) / 256, 256, 0, stream>>>((const uint*)h2b, as2, ad2, asrc2, adst2, N);
    k_agg2<<<(N + 3) / 4, 256, 0, stream>>>((const uint*)h2b, asrc2, adst2, rowptr, csr, b2,
                                            (float2*)out, N);
}

// Round 8
// 273.635 us; speedup vs baseline: 1.1349x; 1.1349x over previous
//
#include <hip/hip_runtime.h>
#include <hip/hip_bf16.h>
#include <math.h>

// ---------------------------------------------------------------------------
// 2-layer GAT on MI355X.
// R7: revert to R5 structure (streamed p1/p2 from k_score1/2 — R6's in-kernel
// shfl softmax put ds_bpermute on the per-edge critical path, +80% time).
// New: agg kernels process 2 edges/wave (half=lane>>5, readlane+select, no
// shfl in loop) -> VMEM instrs per edge halved, VALU/edge ~7 vs ~11.
// ---------------------------------------------------------------------------

typedef __attribute__((ext_vector_type(8))) short short8;
typedef __attribute__((ext_vector_type(4))) float f32x4;

__device__ __forceinline__ float bflo(uint u) { return __uint_as_float(u << 16); }
__device__ __forceinline__ float bfhi(uint u) { return __uint_as_float(u & 0xffff0000u); }
__device__ __forceinline__ ushort f2bf(float f) {  // RNE f32->bf16
    uint u = __float_as_uint(f);
    u += 0x7fff + ((u >> 16) & 1);
    return (ushort)(u >> 16);
}
#define LOG2E 1.44269504088896f

// ----------------------------- CSR build ----------------------------------
#define CSR_CAP 4096

__global__ __launch_bounds__(256) void k_bhist(const int* __restrict__ dst, int e,
                                               int* __restrict__ bcount) {
    __shared__ int h[1024];
    int t = threadIdx.x;
    for (int i = t; i < 1024; i += 256) h[i] = 0;
    __syncthreads();
    int c0 = blockIdx.x * 4096, c1 = min(c0 + 4096, e);
    for (int i = c0 + t; i < c1; i += 256) atomicAdd(&h[dst[i] >> 7], 1);
    __syncthreads();
    for (int i = t; i < 1024; i += 256)
        if (h[i]) atomicAdd(&bcount[i], h[i]);
}

__global__ __launch_bounds__(256) void k_bscan(const int* __restrict__ bcount, int nb, int n,
                                               int* __restrict__ ebase, int* __restrict__ ecur,
                                               int* __restrict__ cbase) {
    __shared__ int ae[1024], be[1024], ac[1024], bc[1024];
    int t = threadIdx.x;
    for (int i = t; i < 1024; i += 256) {
        int v = 0, nn = 0;
        if (i < nb) {
            v = bcount[i];
            nn = min(128, n - (i << 7));
        }
        ae[i] = v;
        ac[i] = v + nn;
    }
    __syncthreads();
    int* pa = ae; int* qa = be; int* pc = ac; int* qc = bc;
    for (int off = 1; off < 1024; off <<= 1) {
        for (int i = t; i < 1024; i += 256) {
            int va = pa[i], vc = pc[i];
            if (i >= off) { va += pa[i - off]; vc += pc[i - off]; }
            qa[i] = va; qc[i] = vc;
        }
        __syncthreads();
        int* tm = pa; pa = qa; qa = tm;
        tm = pc; pc = qc; qc = tm;
    }
    for (int i = t; i < 1024; i += 256) {
        if (i < nb) {
            int ea = (i == 0) ? 0 : pa[i - 1];
            int ca = (i == 0) ? 0 : pc[i - 1];
            ebase[i] = ea; ecur[i] = ea; cbase[i] = ca;
        }
    }
}

// entry packed as (src << 7) | (dst & 127)
__global__ __launch_bounds__(256) void k_part(const int* __restrict__ src,
                                              const int* __restrict__ dst, int e,
                                              int* __restrict__ ecur, int* __restrict__ ebuf) {
    __shared__ int h[1024];
    __shared__ int base[1024];
    int t = threadIdx.x;
    int c0 = blockIdx.x * 4096, c1 = min(c0 + 4096, e);
    for (int i = t; i < 1024; i += 256) h[i] = 0;
    __syncthreads();
    for (int i = c0 + t; i < c1; i += 256) atomicAdd(&h[dst[i] >> 7], 1);
    __syncthreads();
    for (int i = t; i < 1024; i += 256) {
        int c = h[i];
        base[i] = c ? atomicAdd(&ecur[i], c) : 0;
        h[i] = 0;
    }
    __syncthreads();
    for (int i = c0 + t; i < c1; i += 256) {
        int d = dst[i], b = d >> 7;
        int r = atomicAdd(&h[b], 1);
        ebuf[base[b] + r] = (src[i] << 7) | (d & 127);
    }
}

__global__ __launch_bounds__(256) void k_build(const int* __restrict__ ebuf,
                                               const int* __restrict__ bcount,
                                               const int* __restrict__ ebase,
                                               const int* __restrict__ cbase,
                                               int* __restrict__ rowptr,
                                               int* __restrict__ csr,
                                               int* __restrict__ dstid, int n, int nb) {
    __shared__ int cnt[128];
    __shared__ int sc[128], sc2[128];
    __shared__ int csr_l[CSR_CAP];
    __shared__ int dst_l[CSR_CAP];
    int b = blockIdx.x, t = threadIdx.x;
    int n0 = b << 7;
    int nn = min(128, n - n0);
    int ec = bcount[b], eb = ebase[b], cb = cbase[b];
    if (t < 128) cnt[t] = 0;
    __syncthreads();
    for (int i = t; i < ec; i += 256) atomicAdd(&cnt[ebuf[eb + i] & 127], 1);
    __syncthreads();
    if (t < 128) sc[t] = (t < nn) ? cnt[t] + 1 : 0;
    __syncthreads();
    int* p = sc; int* q = sc2;
    for (int off = 1; off < 128; off <<= 1) {
        if (t < 128) {
            int v = p[t];
            if (t >= off) v += p[t - off];
            q[t] = v;
        }
        __syncthreads();
        int* tm = p; p = q; q = tm;
    }
    int total = p[127];  // == ec + nn
    if (total <= CSR_CAP) {
        if (t < nn) {
            int off = (t == 0) ? 0 : p[t - 1];
            rowptr[n0 + t] = cb + off;
            csr_l[off] = n0 + t;   // self-loop
            dst_l[off] = n0 + t;
            cnt[t] = off + 1;
        }
        __syncthreads();
        for (int i = t; i < ec; i += 256) {
            int v = ebuf[eb + i];
            int d = v & 127;
            int s = atomicAdd(&cnt[d], 1);
            csr_l[s] = v >> 7;
            dst_l[s] = n0 + d;
        }
        __syncthreads();
        for (int i = t; i < total; i += 256) {
            csr[cb + i] = csr_l[i];
            dstid[cb + i] = dst_l[i];
        }
    } else {  // fallback (never taken for random graphs)
        if (t < nn) {
            int off = (t == 0) ? 0 : p[t - 1];
            rowptr[n0 + t] = cb + off;
            csr[cb + off] = n0 + t;
            dstid[cb + off] = n0 + t;
            cnt[t] = off + 1;
        }
        __syncthreads();
        for (int i = t; i < ec; i += 256) {
            int v = ebuf[eb + i];
            int d = v & 127;
            int s = atomicAdd(&cnt[d], 1);
            csr[cb + s] = v >> 7;
            dstid[cb + s] = n0 + d;
        }
    }
    if (b == nb - 1 && t == 0) rowptr[n] = cb + total;
}

// --------------------------- MFMA GEMM -------------------------------------
template <int COLS, bool XBF16>
__global__ __launch_bounds__(256) void k_gemm_mfma(const void* __restrict__ Xv,
                                                   const float* __restrict__ W,
                                                   ushort* __restrict__ Y, int n) {
    __shared__ ushort As[128][136];
    __shared__ ushort Ws[COLS][136];   // W^T: [col][k]
    const int t = threadIdx.x;
    const int row0 = blockIdx.x * 128;
    if constexpr (!XBF16) {
        const float* X = (const float*)Xv;
#pragma unroll
        for (int q = 0; q < 16; q++) {
            int idx = t + q * 256;
            int r = idx >> 5, c4 = (idx & 31) * 4;
            float4 xv = make_float4(0.f, 0.f, 0.f, 0.f);
            if (row0 + r < n) xv = *reinterpret_cast<const float4*>(&X[(size_t)(row0 + r) * 128 + c4]);
            ushort4 w4 = make_ushort4(f2bf(xv.x), f2bf(xv.y), f2bf(xv.z), f2bf(xv.w));
            *reinterpret_cast<ushort4*>(&As[r][c4]) = w4;
        }
    } else {
        const ushort* X = (const ushort*)Xv;
#pragma unroll
        for (int q = 0; q < 8; q++) {
            int idx = t + q * 256;
            int r = idx >> 4, c8 = (idx & 15) * 8;
            uint4 v = make_uint4(0u, 0u, 0u, 0u);
            if (row0 + r < n) v = *reinterpret_cast<const uint4*>(&X[(size_t)(row0 + r) * 128 + c8]);
            *reinterpret_cast<uint4*>(&As[r][c8]) = v;
        }
    }
    for (int i = t; i < 128 * COLS; i += 256) {
        int k = i / COLS, nc = i % COLS;
        Ws[nc][k] = f2bf(W[i]);
    }
    __syncthreads();
    const int w = t >> 6, l = t & 63;
    const int lr = l & 15;
    const int lk = (l >> 4) * 8;
    f32x4 acc[2][COLS / 16];
#pragma unroll
    for (int m = 0; m < 2; m++)
#pragma unroll
        for (int nb = 0; nb < COLS / 16; nb++) acc[m][nb] = (f32x4){0.f, 0.f, 0.f, 0.f};
#pragma unroll
    for (int kc = 0; kc < 128; kc += 32) {
        short8 a0 = *reinterpret_cast<const short8*>(&As[w * 32 + lr][kc + lk]);
        short8 a1 = *reinterpret_cast<const short8*>(&As[w * 32 + 16 + lr][kc + lk]);
#pragma unroll
        for (int nb = 0; nb < COLS / 16; nb++) {
            short8 bf = *reinterpret_cast<const short8*>(&Ws[nb * 16 + lr][kc + lk]);
            acc[0][nb] = __builtin_amdgcn_mfma_f32_16x16x32_bf16(a0, bf, acc[0][nb], 0, 0, 0);
            acc[1][nb] = __builtin_amdgcn_mfma_f32_16x16x32_bf16(a1, bf, acc[1][nb], 0, 0, 0);
        }
    }
#pragma unroll
    for (int m = 0; m < 2; m++)
#pragma unroll
        for (int j = 0; j < 4; j++) {
            int r = row0 + w * 32 + m * 16 + (l >> 4) * 4 + j;
            if (r < n) {
#pragma unroll
                for (int nb = 0; nb < COLS / 16; nb++)
                    Y[(size_t)r * COLS + nb * 16 + lr] = f2bf(acc[m][nb][j]);
            }
        }
}

// --------------------------- attention scores ------------------------------
// Written pre-scaled by log2(e): score kernels use native exp2.
__global__ void k_attn1(const uint* __restrict__ hu, const float* __restrict__ a_src,
                        const float* __restrict__ a_dst, float* __restrict__ asrc,
                        float* __restrict__ adst, int n) {
    int t = blockIdx.x * 256 + threadIdx.x;
    if (t >= n * 8) return;
    int node = t >> 3, hd = t & 7;
    const uint* hp = hu + (size_t)node * 64 + hd * 8;
    float s1 = 0.f, s2 = 0.f;
#pragma unroll
    for (int q = 0; q < 8; q++) {
        uint u = hp[q];
        float v0 = bflo(u), v1 = bfhi(u);
        s1 = fmaf(v0, a_src[hd * 16 + 2 * q], s1);
        s1 = fmaf(v1, a_src[hd * 16 + 2 * q + 1], s1);
        s2 = fmaf(v0, a_dst[hd * 16 + 2 * q], s2);
        s2 = fmaf(v1, a_dst[hd * 16 + 2 * q + 1], s2);
    }
    asrc[t] = s1 * LOG2E;
    adst[t] = s2 * LOG2E;
}
__global__ void k_attn2(const uint* __restrict__ hu, const float* __restrict__ a_src,
                        const float* __restrict__ a_dst, float* __restrict__ asrc,
                        float* __restrict__ adst, int n) {
    int t = blockIdx.x * 256 + threadIdx.x;
    if (t >= n * 8) return;
    int node = t >> 3, j = t & 7;
    const uint* hp = hu + (size_t)node * 32 + j * 4;
    float s1 = 0.f, s2 = 0.f;
#pragma unroll
    for (int q = 0; q < 4; q++) {
        uint u = hp[q];
        float v0 = bflo(u), v1 = bfhi(u);
        s1 = fmaf(v0, a_src[j * 8 + 2 * q], s1);
        s1 = fmaf(v1, a_src[j * 8 + 2 * q + 1], s1);
        s2 = fmaf(v0, a_dst[j * 8 + 2 * q], s2);
        s2 = fmaf(v1, a_dst[j * 8 + 2 * q + 1], s2);
    }
#pragma unroll
    for (int o = 1; o < 8; o <<= 1) {
        s1 += __shfl_xor(s1, o);
        s2 += __shfl_xor(s2, o);
    }
    if (j == 0) { asrc[node] = s1 * LOG2E; adst[node] = s2 * LOG2E; }
}

// ------------------------ edge score precompute ----------------------------
__global__ void k_score1(const int* __restrict__ csr, const int* __restrict__ dstid,
                         const float* __restrict__ asrc, const float* __restrict__ adst,
                         _Float16* __restrict__ p1, int tot8) {
    int t = blockIdx.x * 256 + threadIdx.x;
    if (t >= tot8) return;
    int slot = t >> 3, hd = t & 7;
    int s = csr[slot], d = dstid[slot];
    float e = asrc[s * 8 + hd] + adst[d * 8 + hd];
    e = fmaxf(e, 0.2f * e);
    p1[t] = (_Float16)exp2f(e);
}
__global__ void k_score2(const int* __restrict__ csr, const int* __restrict__ dstid,
                         const float* __restrict__ asrc, const float* __restrict__ adst,
                         float* __restrict__ p2, int tot) {
    int t = blockIdx.x * 256 + threadIdx.x;
    if (t >= tot) return;
    float e = asrc[csr[t]] + adst[dstid[t]];
    e = fmaxf(e, 0.2f * e);
    p2[t] = exp2f(e);
}

// ------------------------ aggregation --------------------------------------
// conv1: one wave per dst, 2 edges in flight (half = lane>>5). 32 lanes own
// 4 channels each (uint2 gather = full 256B row per edge per half-wave).
// Indices via coalesced csr fetch + SGPR-indexed readlane (no shfl in loop);
// p1 streamed with immediate-offset loads. Halves merge via shfl_xor(32).
__global__ __launch_bounds__(256) void k_agg1(
    const uint2* __restrict__ hu2, const _Float16* __restrict__ p1,
    const int* __restrict__ rowptr, const int* __restrict__ csr,
    const float* __restrict__ b1, uint2* __restrict__ x2, int n) {
    int wid = (blockIdx.x * 256 + threadIdx.x) >> 6;
    if (wid >= n) return;
    int lane = threadIdx.x & 63;
    int half = lane >> 5, cl = lane & 31;
    int hd = cl >> 2;
    int beg = rowptr[wid], end = rowptr[wid + 1];
    float s = 0.f, a0 = 0.f, a1 = 0.f, a2 = 0.f, a3 = 0.f;
    for (int base = beg; base < end; base += 64) {
        int cnt = min(64, end - base);
        int vidx = csr[base + min(lane, cnt - 1)];
        const _Float16* pp = p1 + (size_t)(base + half) * 8 + hd;
        int j = 0;
        for (; j + 8 <= cnt; j += 8) {
#pragma unroll
            for (int q = 0; q < 4; q++) {
                int e0 = j + 2 * q;
                int sA = __builtin_amdgcn_readlane(vidx, e0);
                int sB = __builtin_amdgcn_readlane(vidx, e0 + 1);
                int se = half ? sB : sA;
                float pe = (float)pp[e0 * 8];
                uint2 u = hu2[(uint)se * 32u + cl];
                s += pe;
                a0 = fmaf(pe, bflo(u.x), a0);
                a1 = fmaf(pe, bfhi(u.x), a1);
                a2 = fmaf(pe, bflo(u.y), a2);
                a3 = fmaf(pe, bfhi(u.y), a3);
            }
        }
        for (; j < cnt; j += 2) {
            int sA = __builtin_amdgcn_readlane(vidx, j);
            int sB = __builtin_amdgcn_readlane(vidx, min(j + 1, cnt - 1));
            int se = half ? sB : sA;
            bool live = (j + half) < cnt;
            float pe = live ? (float)pp[j * 8] : 0.f;
            uint2 u = hu2[(uint)se * 32u + cl];
            s += pe;
            a0 = fmaf(pe, bflo(u.x), a0);
            a1 = fmaf(pe, bfhi(u.x), a1);
            a2 = fmaf(pe, bflo(u.y), a2);
            a3 = fmaf(pe, bfhi(u.y), a3);
        }
    }
    s  += __shfl_xor(s, 32);
    a0 += __shfl_xor(a0, 32);
    a1 += __shfl_xor(a1, 32);
    a2 += __shfl_xor(a2, 32);
    a3 += __shfl_xor(a3, 32);
    if (half == 0) {
        float inv = 1.f / (s + 1e-16f);
        float o0 = a0 * inv + b1[4 * cl + 0];
        float o1 = a1 * inv + b1[4 * cl + 1];
        float o2 = a2 * inv + b1[4 * cl + 2];
        float o3 = a3 * inv + b1[4 * cl + 3];
        o0 = o0 > 0.f ? o0 : (__expf(o0) - 1.f);   // ELU
        o1 = o1 > 0.f ? o1 : (__expf(o1) - 1.f);
        o2 = o2 > 0.f ? o2 : (__expf(o2) - 1.f);
        o3 = o3 > 0.f ? o3 : (__expf(o3) - 1.f);
        uint2 pk;
        pk.x = (uint)f2bf(o0) | ((uint)f2bf(o1) << 16);
        pk.y = (uint)f2bf(o2) | ((uint)f2bf(o3) << 16);
        x2[(uint)wid * 32u + cl] = pk;
    }
}
// conv2: one wave per dst, 2 edges in flight; 32 lanes own 2 channels (uint).
__global__ __launch_bounds__(256) void k_agg2(
    const uint* __restrict__ hb, const float* __restrict__ p2,
    const int* __restrict__ rowptr, const int* __restrict__ csr,
    const float* __restrict__ b2, float2* __restrict__ out, int n) {
    int wid = (blockIdx.x * 256 + threadIdx.x) >> 6;
    if (wid >= n) return;
    int lane = threadIdx.x & 63;
    int half = lane >> 5, cl = lane & 31;
    int beg = rowptr[wid], end = rowptr[wid + 1];
    float s = 0.f, a0 = 0.f, a1 = 0.f;
    for (int base = beg; base < end; base += 64) {
        int cnt = min(64, end - base);
        int vidx = csr[base + min(lane, cnt - 1)];
        const float* pp = p2 + base + half;
        int j = 0;
        for (; j + 8 <= cnt; j += 8) {
#pragma unroll
            for (int q = 0; q < 4; q++) {
                int e0 = j + 2 * q;
                int sA = __builtin_amdgcn_readlane(vidx, e0);
                int sB = __builtin_amdgcn_readlane(vidx, e0 + 1);
                int se = half ? sB : sA;
                float pe = pp[e0];
                uint u = hb[(uint)se * 32u + cl];
                s += pe;
                a0 = fmaf(pe, bflo(u), a0);
                a1 = fmaf(pe, bfhi(u), a1);
            }
        }
        for (; j < cnt; j += 2) {
            int sA = __builtin_amdgcn_readlane(vidx, j);
            int sB = __builtin_amdgcn_readlane(vidx, min(j + 1, cnt - 1));
            int se = half ? sB : sA;
            bool live = (j + half) < cnt;
            float pe = live ? pp[j] : 0.f;
            uint u = hb[(uint)se * 32u + cl];
            s += pe;
            a0 = fmaf(pe, bflo(u), a0);
            a1 = fmaf(pe, bfhi(u), a1);
        }
    }
    s  += __shfl_xor(s, 32);
    a0 += __shfl_xor(a0, 32);
    a1 += __shfl_xor(a1, 32);
    if (half == 0) {
        float inv = 1.f / (s + 1e-16f);
        out[(uint)wid * 32u + cl] = make_float2(a0 * inv + b2[2 * cl],
                                                a1 * inv + b2[2 * cl + 1]);
    }
}

// ------------------------------- launch -------------------------------------
extern "C" void kernel_launch(void* const* d_in, const int* in_sizes, int n_in,
                              void* d_out, int out_size, void* d_ws, size_t ws_size,
                              hipStream_t stream) {
    const float* x   = (const float*)d_in[0];
    const int*   ei  = (const int*)d_in[1];
    const float* W1  = (const float*)d_in[2];
    const float* as1 = (const float*)d_in[3];
    const float* ad1 = (const float*)d_in[4];
    const float* b1  = (const float*)d_in[5];
    const float* W2  = (const float*)d_in[6];
    const float* as2 = (const float*)d_in[7];
    const float* ad2 = (const float*)d_in[8];
    const float* b2  = (const float*)d_in[9];
    float* out = (float*)d_out;

    int N = in_sizes[0] / 128;
    int E = in_sizes[1] / 2;
    int TOT = E + N;
    const int* src = ei;
    const int* dst = ei + E;

    char* p = (char*)d_ws;
    auto alloc = [&](size_t bytes) {
        char* r = p;
        p += (bytes + 255) & ~size_t(255);
        return r;
    };
    ushort* h1b  = (ushort*)alloc((size_t)N * 128 * 2);
    ushort* h2b  = (ushort*)alloc((size_t)N * 64 * 2);
    ushort* x2b  = (ushort*)alloc((size_t)N * 128 * 2);
    float* asrc1 = (float*)alloc((size_t)N * 8 * 4);
    float* adst1 = (float*)alloc((size_t)N * 8 * 4);
    float* asrc2 = (float*)alloc((size_t)N * 4);
    float* adst2 = (float*)alloc((size_t)N * 4);
    int* rowptr  = (int*)alloc((size_t)(N + 1) * 4);
    int* csr     = (int*)alloc((size_t)TOT * 4);
    int* dstid   = (int*)alloc((size_t)TOT * 4);
    int* ebuf    = (int*)alloc((size_t)TOT * 4);   // reused as p2 after k_build
    _Float16* p1 = (_Float16*)alloc(((size_t)TOT * 8 + 16) * 2);  // +slack for tail
    int* bcount  = (int*)alloc(1024 * 4);
    int* ebase   = (int*)alloc(1024 * 4);
    int* ecur    = (int*)alloc(1024 * 4);
    int* cbase   = (int*)alloc(1024 * 4);
    float* p2    = (float*)ebuf;

    int NB = (N + 127) >> 7;
    int nbk = (E + 4095) / 4096;

    // CSR build
    hipMemsetAsync(bcount, 0, 1024 * 4, stream);
    k_bhist<<<nbk, 256, 0, stream>>>(dst, E, bcount);
    k_bscan<<<1, 256, 0, stream>>>(bcount, NB, N, ebase, ecur, cbase);
    k_part<<<nbk, 256, 0, stream>>>(src, dst, E, ecur, ebuf);
    k_build<<<NB, 256, 0, stream>>>(ebuf, bcount, ebase, cbase, rowptr, csr, dstid, N, NB);

    int gb = (N + 127) / 128;
    // conv1
    k_gemm_mfma<128, false><<<gb, 256, 0, stream>>>(x, W1, h1b, N);
    k_attn1<<<(N * 8 + 255) / 256, 256, 0, stream>>>((const uint*)h1b, as1, ad1, asrc1, adst1, N);
    k_score1<<<((size_t)TOT * 8 + 255) / 256, 256, 0, stream>>>(csr, dstid, asrc1, adst1, p1, TOT * 8);
    k_agg1<<<(N + 3) / 4, 256, 0, stream>>>((const uint2*)h1b, p1, rowptr, csr, b1, (uint2*)x2b, N);

    // conv2
    k_gemm_mfma<64, true><<<gb, 256, 0, stream>>>(x2b, W2, h2b, N);
    k_attn2<<<(N * 8 + 255) / 256, 256, 0, stream>>>((const uint*)h2b, as2, ad2, asrc2, adst2, N);
    k_score2<<<(TOT + 255) / 256, 256, 0, stream>>>(csr, dstid, asrc2, adst2, p2, TOT);
    k_agg2<<<(N + 3) / 4, 256, 0, stream>>>((const uint*)h2b, p2, rowptr, csr, b2, (float2*)out, N);
}

// Round 9
// 269.857 us; speedup vs baseline: 1.1507x; 1.0140x over previous
//
#include <hip/hip_runtime.h>
#include <hip/hip_bf16.h>
#include <math.h>

// ---------------------------------------------------------------------------
// 2-layer GAT on MI355X.
// R9: agg kernels back to the validated R5 structure (64-lane, streamed p,
// readlane index broadcast) with unroll deepened 4->8 (more gathers in
// flight; agg is ~35-45% memory-wait at ~6.5 TB/s delivered). k_part chunk
// doubled (8192 edges / 512 threads) to halve scatter write amplification.
// ---------------------------------------------------------------------------

typedef __attribute__((ext_vector_type(8))) short short8;
typedef __attribute__((ext_vector_type(4))) float f32x4;

__device__ __forceinline__ float bflo(uint u) { return __uint_as_float(u << 16); }
__device__ __forceinline__ float bfhi(uint u) { return __uint_as_float(u & 0xffff0000u); }
__device__ __forceinline__ float bf1(ushort v) { return __uint_as_float(((uint)v) << 16); }
__device__ __forceinline__ ushort f2bf(float f) {  // RNE f32->bf16
    uint u = __float_as_uint(f);
    u += 0x7fff + ((u >> 16) & 1);
    return (ushort)(u >> 16);
}
#define LOG2E 1.44269504088896f

// ----------------------------- CSR build ----------------------------------
#define CSR_CAP 4096

__global__ __launch_bounds__(256) void k_bhist(const int* __restrict__ dst, int e,
                                               int* __restrict__ bcount) {
    __shared__ int h[1024];
    int t = threadIdx.x;
    for (int i = t; i < 1024; i += 256) h[i] = 0;
    __syncthreads();
    int c0 = blockIdx.x * 4096, c1 = min(c0 + 4096, e);
    for (int i = c0 + t; i < c1; i += 256) atomicAdd(&h[dst[i] >> 7], 1);
    __syncthreads();
    for (int i = t; i < 1024; i += 256)
        if (h[i]) atomicAdd(&bcount[i], h[i]);
}

__global__ __launch_bounds__(256) void k_bscan(const int* __restrict__ bcount, int nb, int n,
                                               int* __restrict__ ebase, int* __restrict__ ecur,
                                               int* __restrict__ cbase) {
    __shared__ int ae[1024], be[1024], ac[1024], bc[1024];
    int t = threadIdx.x;
    for (int i = t; i < 1024; i += 256) {
        int v = 0, nn = 0;
        if (i < nb) {
            v = bcount[i];
            nn = min(128, n - (i << 7));
        }
        ae[i] = v;
        ac[i] = v + nn;
    }
    __syncthreads();
    int* pa = ae; int* qa = be; int* pc = ac; int* qc = bc;
    for (int off = 1; off < 1024; off <<= 1) {
        for (int i = t; i < 1024; i += 256) {
            int va = pa[i], vc = pc[i];
            if (i >= off) { va += pa[i - off]; vc += pc[i - off]; }
            qa[i] = va; qc[i] = vc;
        }
        __syncthreads();
        int* tm = pa; pa = qa; qa = tm;
        tm = pc; pc = qc; qc = tm;
    }
    for (int i = t; i < 1024; i += 256) {
        if (i < nb) {
            int ea = (i == 0) ? 0 : pa[i - 1];
            int ca = (i == 0) ? 0 : pc[i - 1];
            ebase[i] = ea; ecur[i] = ea; cbase[i] = ca;
        }
    }
}

// entry packed as (src << 7) | (dst & 127); 8192-edge chunks, 512 threads.
__global__ __launch_bounds__(512) void k_part(const int* __restrict__ src,
                                              const int* __restrict__ dst, int e,
                                              int* __restrict__ ecur, int* __restrict__ ebuf) {
    __shared__ int h[1024];
    __shared__ int base[1024];
    int t = threadIdx.x;
    int c0 = blockIdx.x * 8192, c1 = min(c0 + 8192, e);
    for (int i = t; i < 1024; i += 512) h[i] = 0;
    __syncthreads();
    for (int i = c0 + t; i < c1; i += 512) atomicAdd(&h[dst[i] >> 7], 1);
    __syncthreads();
    for (int i = t; i < 1024; i += 512) {
        int c = h[i];
        base[i] = c ? atomicAdd(&ecur[i], c) : 0;
        h[i] = 0;
    }
    __syncthreads();
    for (int i = c0 + t; i < c1; i += 512) {
        int d = dst[i], b = d >> 7;
        int r = atomicAdd(&h[b], 1);
        ebuf[base[b] + r] = (src[i] << 7) | (d & 127);
    }
}

__global__ __launch_bounds__(256) void k_build(const int* __restrict__ ebuf,
                                               const int* __restrict__ bcount,
                                               const int* __restrict__ ebase,
                                               const int* __restrict__ cbase,
                                               int* __restrict__ rowptr,
                                               int* __restrict__ csr,
                                               int* __restrict__ dstid, int n, int nb) {
    __shared__ int cnt[128];
    __shared__ int sc[128], sc2[128];
    __shared__ int csr_l[CSR_CAP];
    __shared__ int dst_l[CSR_CAP];
    int b = blockIdx.x, t = threadIdx.x;
    int n0 = b << 7;
    int nn = min(128, n - n0);
    int ec = bcount[b], eb = ebase[b], cb = cbase[b];
    if (t < 128) cnt[t] = 0;
    __syncthreads();
    for (int i = t; i < ec; i += 256) atomicAdd(&cnt[ebuf[eb + i] & 127], 1);
    __syncthreads();
    if (t < 128) sc[t] = (t < nn) ? cnt[t] + 1 : 0;
    __syncthreads();
    int* p = sc; int* q = sc2;
    for (int off = 1; off < 128; off <<= 1) {
        if (t < 128) {
            int v = p[t];
            if (t >= off) v += p[t - off];
            q[t] = v;
        }
        __syncthreads();
        int* tm = p; p = q; q = tm;
    }
    int total = p[127];  // == ec + nn
    if (total <= CSR_CAP) {
        if (t < nn) {
            int off = (t == 0) ? 0 : p[t - 1];
            rowptr[n0 + t] = cb + off;
            csr_l[off] = n0 + t;   // self-loop
            dst_l[off] = n0 + t;
            cnt[t] = off + 1;
        }
        __syncthreads();
        for (int i = t; i < ec; i += 256) {
            int v = ebuf[eb + i];
            int d = v & 127;
            int s = atomicAdd(&cnt[d], 1);
            csr_l[s] = v >> 7;
            dst_l[s] = n0 + d;
        }
        __syncthreads();
        for (int i = t; i < total; i += 256) {
            csr[cb + i] = csr_l[i];
            dstid[cb + i] = dst_l[i];
        }
    } else {  // fallback (never taken for random graphs)
        if (t < nn) {
            int off = (t == 0) ? 0 : p[t - 1];
            rowptr[n0 + t] = cb + off;
            csr[cb + off] = n0 + t;
            dstid[cb + off] = n0 + t;
            cnt[t] = off + 1;
        }
        __syncthreads();
        for (int i = t; i < ec; i += 256) {
            int v = ebuf[eb + i];
            int d = v & 127;
            int s = atomicAdd(&cnt[d], 1);
            csr[cb + s] = v >> 7;
            dstid[cb + s] = n0 + d;
        }
    }
    if (b == nb - 1 && t == 0) rowptr[n] = cb + total;
}

// --------------------------- MFMA GEMM -------------------------------------
template <int COLS, bool XBF16>
__global__ __launch_bounds__(256) void k_gemm_mfma(const void* __restrict__ Xv,
                                                   const float* __restrict__ W,
                                                   ushort* __restrict__ Y, int n) {
    __shared__ ushort As[128][136];
    __shared__ ushort Ws[COLS][136];   // W^T: [col][k]
    const int t = threadIdx.x;
    const int row0 = blockIdx.x * 128;
    if constexpr (!XBF16) {
        const float* X = (const float*)Xv;
#pragma unroll
        for (int q = 0; q < 16; q++) {
            int idx = t + q * 256;
            int r = idx >> 5, c4 = (idx & 31) * 4;
            float4 xv = make_float4(0.f, 0.f, 0.f, 0.f);
            if (row0 + r < n) xv = *reinterpret_cast<const float4*>(&X[(size_t)(row0 + r) * 128 + c4]);
            ushort4 w4 = make_ushort4(f2bf(xv.x), f2bf(xv.y), f2bf(xv.z), f2bf(xv.w));
            *reinterpret_cast<ushort4*>(&As[r][c4]) = w4;
        }
    } else {
        const ushort* X = (const ushort*)Xv;
#pragma unroll
        for (int q = 0; q < 8; q++) {
            int idx = t + q * 256;
            int r = idx >> 4, c8 = (idx & 15) * 8;
            uint4 v = make_uint4(0u, 0u, 0u, 0u);
            if (row0 + r < n) v = *reinterpret_cast<const uint4*>(&X[(size_t)(row0 + r) * 128 + c8]);
            *reinterpret_cast<uint4*>(&As[r][c8]) = v;
        }
    }
    for (int i = t; i < 128 * COLS; i += 256) {
        int k = i / COLS, nc = i % COLS;
        Ws[nc][k] = f2bf(W[i]);
    }
    __syncthreads();
    const int w = t >> 6, l = t & 63;
    const int lr = l & 15;
    const int lk = (l >> 4) * 8;
    f32x4 acc[2][COLS / 16];
#pragma unroll
    for (int m = 0; m < 2; m++)
#pragma unroll
        for (int nb = 0; nb < COLS / 16; nb++) acc[m][nb] = (f32x4){0.f, 0.f, 0.f, 0.f};
#pragma unroll
    for (int kc = 0; kc < 128; kc += 32) {
        short8 a0 = *reinterpret_cast<const short8*>(&As[w * 32 + lr][kc + lk]);
        short8 a1 = *reinterpret_cast<const short8*>(&As[w * 32 + 16 + lr][kc + lk]);
#pragma unroll
        for (int nb = 0; nb < COLS / 16; nb++) {
            short8 bf = *reinterpret_cast<const short8*>(&Ws[nb * 16 + lr][kc + lk]);
            acc[0][nb] = __builtin_amdgcn_mfma_f32_16x16x32_bf16(a0, bf, acc[0][nb], 0, 0, 0);
            acc[1][nb] = __builtin_amdgcn_mfma_f32_16x16x32_bf16(a1, bf, acc[1][nb], 0, 0, 0);
        }
    }
#pragma unroll
    for (int m = 0; m < 2; m++)
#pragma unroll
        for (int j = 0; j < 4; j++) {
            int r = row0 + w * 32 + m * 16 + (l >> 4) * 4 + j;
            if (r < n) {
#pragma unroll
                for (int nb = 0; nb < COLS / 16; nb++)
                    Y[(size_t)r * COLS + nb * 16 + lr] = f2bf(acc[m][nb][j]);
            }
        }
}

// --------------------------- attention scores ------------------------------
__global__ void k_attn1(const uint* __restrict__ hu, const float* __restrict__ a_src,
                        const float* __restrict__ a_dst, float* __restrict__ asrc,
                        float* __restrict__ adst, int n) {
    int t = blockIdx.x * 256 + threadIdx.x;
    if (t >= n * 8) return;
    int node = t >> 3, hd = t & 7;
    const uint* hp = hu + (size_t)node * 64 + hd * 8;
    float s1 = 0.f, s2 = 0.f;
#pragma unroll
    for (int q = 0; q < 8; q++) {
        uint u = hp[q];
        float v0 = bflo(u), v1 = bfhi(u);
        s1 = fmaf(v0, a_src[hd * 16 + 2 * q], s1);
        s1 = fmaf(v1, a_src[hd * 16 + 2 * q + 1], s1);
        s2 = fmaf(v0, a_dst[hd * 16 + 2 * q], s2);
        s2 = fmaf(v1, a_dst[hd * 16 + 2 * q + 1], s2);
    }
    asrc[t] = s1 * LOG2E;
    adst[t] = s2 * LOG2E;
}
__global__ void k_attn2(const uint* __restrict__ hu, const float* __restrict__ a_src,
                        const float* __restrict__ a_dst, float* __restrict__ asrc,
                        float* __restrict__ adst, int n) {
    int t = blockIdx.x * 256 + threadIdx.x;
    if (t >= n * 8) return;
    int node = t >> 3, j = t & 7;
    const uint* hp = hu + (size_t)node * 32 + j * 4;
    float s1 = 0.f, s2 = 0.f;
#pragma unroll
    for (int q = 0; q < 4; q++) {
        uint u = hp[q];
        float v0 = bflo(u), v1 = bfhi(u);
        s1 = fmaf(v0, a_src[j * 8 + 2 * q], s1);
        s1 = fmaf(v1, a_src[j * 8 + 2 * q + 1], s1);
        s2 = fmaf(v0, a_dst[j * 8 + 2 * q], s2);
        s2 = fmaf(v1, a_dst[j * 8 + 2 * q + 1], s2);
    }
#pragma unroll
    for (int o = 1; o < 8; o <<= 1) {
        s1 += __shfl_xor(s1, o);
        s2 += __shfl_xor(s2, o);
    }
    if (j == 0) { asrc[node] = s1 * LOG2E; adst[node] = s2 * LOG2E; }
}

// ------------------------ edge score precompute ----------------------------
__global__ void k_score1(const int* __restrict__ csr, const int* __restrict__ dstid,
                         const float* __restrict__ asrc, const float* __restrict__ adst,
                         _Float16* __restrict__ p1, int tot8) {
    int t = blockIdx.x * 256 + threadIdx.x;
    if (t >= tot8) return;
    int slot = t >> 3, hd = t & 7;
    int s = csr[slot], d = dstid[slot];
    float e = asrc[s * 8 + hd] + adst[d * 8 + hd];
    e = fmaxf(e, 0.2f * e);
    p1[t] = (_Float16)exp2f(e);
}
__global__ void k_score2(const int* __restrict__ csr, const int* __restrict__ dstid,
                         const float* __restrict__ asrc, const float* __restrict__ adst,
                         float* __restrict__ p2, int tot) {
    int t = blockIdx.x * 256 + threadIdx.x;
    if (t >= tot) return;
    float e = asrc[csr[t]] + adst[dstid[t]];
    e = fmaxf(e, 0.2f * e);
    p2[t] = exp2f(e);
}

// ------------------------ aggregation --------------------------------------
__global__ __launch_bounds__(256) void k_agg1(
    const uint* __restrict__ hu, const _Float16* __restrict__ p1,
    const int* __restrict__ rowptr, const int* __restrict__ csr,
    const float* __restrict__ b1, uint* __restrict__ x2, int n) {
    int wid = (blockIdx.x * 256 + threadIdx.x) >> 6;
    if (wid >= n) return;
    uint lane = threadIdx.x & 63;
    uint c0 = lane * 2;
    uint hd = lane >> 3;
    int beg = rowptr[wid], end = rowptr[wid + 1];
    float s = 0.f, acc0 = 0.f, acc1 = 0.f;
    for (int base = beg; base < end; base += 64) {
        int cnt = min(64, end - base);
        int vidx = ((int)lane < cnt) ? csr[base + lane] : 0;
        const _Float16* pp = p1 + (size_t)base * 8 + hd;
        int j = 0;
        for (; j + 8 <= cnt; j += 8) {
            uint s0 = __builtin_amdgcn_readlane(vidx, j);
            uint s1 = __builtin_amdgcn_readlane(vidx, j + 1);
            uint s2 = __builtin_amdgcn_readlane(vidx, j + 2);
            uint s3 = __builtin_amdgcn_readlane(vidx, j + 3);
            uint s4 = __builtin_amdgcn_readlane(vidx, j + 4);
            uint s5 = __builtin_amdgcn_readlane(vidx, j + 5);
            uint s6 = __builtin_amdgcn_readlane(vidx, j + 6);
            uint s7 = __builtin_amdgcn_readlane(vidx, j + 7);
            uint u0 = hu[s0 * 64u + lane];
            uint u1 = hu[s1 * 64u + lane];
            uint u2 = hu[s2 * 64u + lane];
            uint u3 = hu[s3 * 64u + lane];
            uint u4 = hu[s4 * 64u + lane];
            uint u5 = hu[s5 * 64u + lane];
            uint u6 = hu[s6 * 64u + lane];
            uint u7 = hu[s7 * 64u + lane];
            float q0 = (float)pp[(j + 0) * 8];
            float q1 = (float)pp[(j + 1) * 8];
            float q2 = (float)pp[(j + 2) * 8];
            float q3 = (float)pp[(j + 3) * 8];
            float q4 = (float)pp[(j + 4) * 8];
            float q5 = (float)pp[(j + 5) * 8];
            float q6 = (float)pp[(j + 6) * 8];
            float q7 = (float)pp[(j + 7) * 8];
            s += ((q0 + q1) + (q2 + q3)) + ((q4 + q5) + (q6 + q7));
            acc0 = fmaf(q0, bflo(u0), fmaf(q1, bflo(u1), acc0));
            acc0 = fmaf(q2, bflo(u2), fmaf(q3, bflo(u3), acc0));
            acc0 = fmaf(q4, bflo(u4), fmaf(q5, bflo(u5), acc0));
            acc0 = fmaf(q6, bflo(u6), fmaf(q7, bflo(u7), acc0));
            acc1 = fmaf(q0, bfhi(u0), fmaf(q1, bfhi(u1), acc1));
            acc1 = fmaf(q2, bfhi(u2), fmaf(q3, bfhi(u3), acc1));
            acc1 = fmaf(q4, bfhi(u4), fmaf(q5, bfhi(u5), acc1));
            acc1 = fmaf(q6, bfhi(u6), fmaf(q7, bfhi(u7), acc1));
        }
        for (; j < cnt; ++j) {
            uint s0 = __builtin_amdgcn_readlane(vidx, j);
            float q0 = (float)pp[j * 8];
            uint u0 = hu[s0 * 64u + lane];
            s += q0;
            acc0 = fmaf(q0, bflo(u0), acc0);
            acc1 = fmaf(q0, bfhi(u0), acc1);
        }
    }
    float inv = 1.f / (s + 1e-16f);
    float o0 = acc0 * inv + b1[c0];
    float o1 = acc1 * inv + b1[c0 + 1];
    o0 = o0 > 0.f ? o0 : (__expf(o0) - 1.f);  // ELU
    o1 = o1 > 0.f ? o1 : (__expf(o1) - 1.f);
    union { ushort b[2]; uint u; } pk;
    pk.b[0] = f2bf(o0);
    pk.b[1] = f2bf(o1);
    x2[(uint)wid * 64u + lane] = pk.u;
}
__global__ __launch_bounds__(256) void k_agg2(
    const ushort* __restrict__ hb, const float* __restrict__ p2,
    const int* __restrict__ rowptr, const int* __restrict__ csr,
    const float* __restrict__ b2, float* __restrict__ out, int n) {
    int wid = (blockIdx.x * 256 + threadIdx.x) >> 6;
    if (wid >= n) return;
    uint lane = threadIdx.x & 63;
    int beg = rowptr[wid], end = rowptr[wid + 1];
    float s = 0.f, acc = 0.f;
    for (int base = beg; base < end; base += 64) {
        int cnt = min(64, end - base);
        int vidx = ((int)lane < cnt) ? csr[base + lane] : 0;
        int pvi = ((int)lane < cnt) ? __float_as_int(p2[base + lane]) : 0;
        int j = 0;
        for (; j + 8 <= cnt; j += 8) {
            uint s0 = __builtin_amdgcn_readlane(vidx, j);
            uint s1 = __builtin_amdgcn_readlane(vidx, j + 1);
            uint s2 = __builtin_amdgcn_readlane(vidx, j + 2);
            uint s3 = __builtin_amdgcn_readlane(vidx, j + 3);
            uint s4 = __builtin_amdgcn_readlane(vidx, j + 4);
            uint s5 = __builtin_amdgcn_readlane(vidx, j + 5);
            uint s6 = __builtin_amdgcn_readlane(vidx, j + 6);
            uint s7 = __builtin_amdgcn_readlane(vidx, j + 7);
            float h0 = bf1(hb[s0 * 64u + lane]);
            float h1 = bf1(hb[s1 * 64u + lane]);
            float h2 = bf1(hb[s2 * 64u + lane]);
            float h3 = bf1(hb[s3 * 64u + lane]);
            float h4 = bf1(hb[s4 * 64u + lane]);
            float h5 = bf1(hb[s5 * 64u + lane]);
            float h6 = bf1(hb[s6 * 64u + lane]);
            float h7 = bf1(hb[s7 * 64u + lane]);
            float q0 = __int_as_float(__builtin_amdgcn_readlane(pvi, j));
            float q1 = __int_as_float(__builtin_amdgcn_readlane(pvi, j + 1));
            float q2 = __int_as_float(__builtin_amdgcn_readlane(pvi, j + 2));
            float q3 = __int_as_float(__builtin_amdgcn_readlane(pvi, j + 3));
            float q4 = __int_as_float(__builtin_amdgcn_readlane(pvi, j + 4));
            float q5 = __int_as_float(__builtin_amdgcn_readlane(pvi, j + 5));
            float q6 = __int_as_float(__builtin_amdgcn_readlane(pvi, j + 6));
            float q7 = __int_as_float(__builtin_amdgcn_readlane(pvi, j + 7));
            s += ((q0 + q1) + (q2 + q3)) + ((q4 + q5) + (q6 + q7));
            acc = fmaf(q0, h0, fmaf(q1, h1, acc));
            acc = fmaf(q2, h2, fmaf(q3, h3, acc));
            acc = fmaf(q4, h4, fmaf(q5, h5, acc));
            acc = fmaf(q6, h6, fmaf(q7, h7, acc));
        }
        for (; j < cnt; ++j) {
            uint s0 = __builtin_amdgcn_readlane(vidx, j);
            float q0 = __int_as_float(__builtin_amdgcn_readlane(pvi, j));
            float h0 = bf1(hb[s0 * 64u + lane]);
            s += q0;
            acc = fmaf(q0, h0, acc);
        }
    }
    out[(size_t)wid * 64 + lane] = acc / (s + 1e-16f) + b2[lane];
}

// ------------------------------- launch -------------------------------------
extern "C" void kernel_launch(void* const* d_in, const int* in_sizes, int n_in,
                              void* d_out, int out_size, void* d_ws, size_t ws_size,
                              hipStream_t stream) {
    const float* x   = (const float*)d_in[0];
    const int*   ei  = (const int*)d_in[1];
    const float* W1  = (const float*)d_in[2];
    const float* as1 = (const float*)d_in[3];
    const float* ad1 = (const float*)d_in[4];
    const float* b1  = (const float*)d_in[5];
    const float* W2  = (const float*)d_in[6];
    const float* as2 = (const float*)d_in[7];
    const float* ad2 = (const float*)d_in[8];
    const float* b2  = (const float*)d_in[9];
    float* out = (float*)d_out;

    int N = in_sizes[0] / 128;
    int E = in_sizes[1] / 2;
    int TOT = E + N;
    const int* src = ei;
    const int* dst = ei + E;

    char* p = (char*)d_ws;
    auto alloc = [&](size_t bytes) {
        char* r = p;
        p += (bytes + 255) & ~size_t(255);
        return r;
    };
    ushort* h1b  = (ushort*)alloc((size_t)N * 128 * 2);
    ushort* h2b  = (ushort*)alloc((size_t)N * 64 * 2);
    ushort* x2b  = (ushort*)alloc((size_t)N * 128 * 2);
    float* asrc1 = (float*)alloc((size_t)N * 8 * 4);
    float* adst1 = (float*)alloc((size_t)N * 8 * 4);
    float* asrc2 = (float*)alloc((size_t)N * 4);
    float* adst2 = (float*)alloc((size_t)N * 4);
    int* rowptr  = (int*)alloc((size_t)(N + 1) * 4);
    int* csr     = (int*)alloc((size_t)TOT * 4);
    int* dstid   = (int*)alloc((size_t)TOT * 4);
    int* ebuf    = (int*)alloc((size_t)TOT * 4);   // reused as p2 after k_build
    _Float16* p1 = (_Float16*)alloc(((size_t)TOT * 8 + 16) * 2);
    int* bcount  = (int*)alloc(1024 * 4);
    int* ebase   = (int*)alloc(1024 * 4);
    int* ecur    = (int*)alloc(1024 * 4);
    int* cbase   = (int*)alloc(1024 * 4);
    float* p2    = (float*)ebuf;

    int NB = (N + 127) >> 7;
    int nbk = (E + 4095) / 4096;
    int nbp = (E + 8191) / 8192;

    // CSR build
    hipMemsetAsync(bcount, 0, 1024 * 4, stream);
    k_bhist<<<nbk, 256, 0, stream>>>(dst, E, bcount);
    k_bscan<<<1, 256, 0, stream>>>(bcount, NB, N, ebase, ecur, cbase);
    k_part<<<nbp, 512, 0, stream>>>(src, dst, E, ecur, ebuf);
    k_build<<<NB, 256, 0, stream>>>(ebuf, bcount, ebase, cbase, rowptr, csr, dstid, N, NB);

    int gb = (N + 127) / 128;
    // conv1
    k_gemm_mfma<128, false><<<gb, 256, 0, stream>>>(x, W1, h1b, N);
    k_attn1<<<(N * 8 + 255) / 256, 256, 0, stream>>>((const uint*)h1b, as1, ad1, asrc1, adst1, N);
    k_score1<<<((size_t)TOT * 8 + 255) / 256, 256, 0, stream>>>(csr, dstid, asrc1, adst1, p1, TOT * 8);
    k_agg1<<<(N + 3) / 4, 256, 0, stream>>>((const uint*)h1b, p1, rowptr, csr, b1, (uint*)x2b, N);

    // conv2
    k_gemm_mfma<64, true><<<gb, 256, 0, stream>>>(x2b, W2, h2b, N);
    k_attn2<<<(N * 8 + 255) / 256, 256, 0, stream>>>((const uint*)h2b, as2, ad2, asrc2, adst2, N);
    k_score2<<<(TOT + 255) / 256, 256, 0, stream>>>(csr, dstid, asrc2, adst2, p2, TOT);
    k_agg2<<<(N + 3) / 4, 256, 0, stream>>>((const ushort*)h2b, p2, rowptr, csr, b2, out, N);
}

// Round 10
// 241.991 us; speedup vs baseline: 1.2833x; 1.1152x over previous
//
#include <hip/hip_runtime.h>
#include <hip/hip_bf16.h>
#include <math.h>

// ---------------------------------------------------------------------------
// 2-layer GAT on MI355X.
// R10: softmax numerators computed INSIDE agg kernels via phase-separated
// LDS staging (per 64-slot block: cooperative p-compute -> lgkmcnt(0) ->
// gather loop with broadcast ds_reads). No per-edge shfl (R6's mistake), no
// streamed p1/p2, no score kernels, no dstid. CSR via bucket sort; GEMMs via
// bf16 MFMA 16x16x32; agg gather loop = validated R9 structure.
// ---------------------------------------------------------------------------

typedef __attribute__((ext_vector_type(8))) short short8;
typedef __attribute__((ext_vector_type(4))) float f32x4;

__device__ __forceinline__ float bflo(uint u) { return __uint_as_float(u << 16); }
__device__ __forceinline__ float bfhi(uint u) { return __uint_as_float(u & 0xffff0000u); }
__device__ __forceinline__ float bf1(ushort v) { return __uint_as_float(((uint)v) << 16); }
__device__ __forceinline__ ushort f2bf(float f) {  // RNE f32->bf16
    uint u = __float_as_uint(f);
    u += 0x7fff + ((u >> 16) & 1);
    return (ushort)(u >> 16);
}
#define LOG2E 1.44269504088896f

// ----------------------------- CSR build ----------------------------------
#define CSR_CAP 4096

__global__ __launch_bounds__(512) void k_bhist(const int* __restrict__ dst, int e,
                                               int* __restrict__ bcount) {
    __shared__ int h[1024];
    int t = threadIdx.x;
    for (int i = t; i < 1024; i += 512) h[i] = 0;
    __syncthreads();
    int c0 = blockIdx.x * 8192, c1 = min(c0 + 8192, e);
    for (int i = c0 + t; i < c1; i += 512) atomicAdd(&h[dst[i] >> 7], 1);
    __syncthreads();
    for (int i = t; i < 1024; i += 512)
        if (h[i]) atomicAdd(&bcount[i], h[i]);
}

__global__ __launch_bounds__(256) void k_bscan(const int* __restrict__ bcount, int nb, int n,
                                               int* __restrict__ ebase, int* __restrict__ ecur,
                                               int* __restrict__ cbase) {
    __shared__ int ae[1024], be[1024], ac[1024], bc[1024];
    int t = threadIdx.x;
    for (int i = t; i < 1024; i += 256) {
        int v = 0, nn = 0;
        if (i < nb) {
            v = bcount[i];
            nn = min(128, n - (i << 7));
        }
        ae[i] = v;
        ac[i] = v + nn;
    }
    __syncthreads();
    int* pa = ae; int* qa = be; int* pc = ac; int* qc = bc;
    for (int off = 1; off < 1024; off <<= 1) {
        for (int i = t; i < 1024; i += 256) {
            int va = pa[i], vc = pc[i];
            if (i >= off) { va += pa[i - off]; vc += pc[i - off]; }
            qa[i] = va; qc[i] = vc;
        }
        __syncthreads();
        int* tm = pa; pa = qa; qa = tm;
        tm = pc; pc = qc; qc = tm;
    }
    for (int i = t; i < 1024; i += 256) {
        if (i < nb) {
            int ea = (i == 0) ? 0 : pa[i - 1];
            int ca = (i == 0) ? 0 : pc[i - 1];
            ebase[i] = ea; ecur[i] = ea; cbase[i] = ca;
        }
    }
}

// entry packed as (src << 7) | (dst & 127); 8192-edge chunks, 512 threads.
__global__ __launch_bounds__(512) void k_part(const int* __restrict__ src,
                                              const int* __restrict__ dst, int e,
                                              int* __restrict__ ecur, int* __restrict__ ebuf) {
    __shared__ int h[1024];
    __shared__ int base[1024];
    int t = threadIdx.x;
    int c0 = blockIdx.x * 8192, c1 = min(c0 + 8192, e);
    for (int i = t; i < 1024; i += 512) h[i] = 0;
    __syncthreads();
    for (int i = c0 + t; i < c1; i += 512) atomicAdd(&h[dst[i] >> 7], 1);
    __syncthreads();
    for (int i = t; i < 1024; i += 512) {
        int c = h[i];
        base[i] = c ? atomicAdd(&ecur[i], c) : 0;
        h[i] = 0;
    }
    __syncthreads();
    for (int i = c0 + t; i < c1; i += 512) {
        int d = dst[i], b = d >> 7;
        int r = atomicAdd(&h[b], 1);
        ebuf[base[b] + r] = (src[i] << 7) | (d & 127);
    }
}

__global__ __launch_bounds__(256) void k_build(const int* __restrict__ ebuf,
                                               const int* __restrict__ bcount,
                                               const int* __restrict__ ebase,
                                               const int* __restrict__ cbase,
                                               int* __restrict__ rowptr,
                                               int* __restrict__ csr, int n, int nb) {
    __shared__ int cnt[128];
    __shared__ int sc[128], sc2[128];
    __shared__ int csr_l[CSR_CAP];
    int b = blockIdx.x, t = threadIdx.x;
    int n0 = b << 7;
    int nn = min(128, n - n0);
    int ec = bcount[b], eb = ebase[b], cb = cbase[b];
    if (t < 128) cnt[t] = 0;
    __syncthreads();
    for (int i = t; i < ec; i += 256) atomicAdd(&cnt[ebuf[eb + i] & 127], 1);
    __syncthreads();
    if (t < 128) sc[t] = (t < nn) ? cnt[t] + 1 : 0;
    __syncthreads();
    int* p = sc; int* q = sc2;
    for (int off = 1; off < 128; off <<= 1) {
        if (t < 128) {
            int v = p[t];
            if (t >= off) v += p[t - off];
            q[t] = v;
        }
        __syncthreads();
        int* tm = p; p = q; q = tm;
    }
    int total = p[127];  // == ec + nn
    if (total <= CSR_CAP) {
        if (t < nn) {
            int off = (t == 0) ? 0 : p[t - 1];
            rowptr[n0 + t] = cb + off;
            csr_l[off] = n0 + t;   // self-loop
            cnt[t] = off + 1;
        }
        __syncthreads();
        for (int i = t; i < ec; i += 256) {
            int v = ebuf[eb + i];
            int s = atomicAdd(&cnt[v & 127], 1);
            csr_l[s] = v >> 7;
        }
        __syncthreads();
        for (int i = t; i < total; i += 256) csr[cb + i] = csr_l[i];
    } else {  // fallback (never taken for random graphs)
        if (t < nn) {
            int off = (t == 0) ? 0 : p[t - 1];
            rowptr[n0 + t] = cb + off;
            csr[cb + off] = n0 + t;
            cnt[t] = off + 1;
        }
        __syncthreads();
        for (int i = t; i < ec; i += 256) {
            int v = ebuf[eb + i];
            int s = atomicAdd(&cnt[v & 127], 1);
            csr[cb + s] = v >> 7;
        }
    }
    if (b == nb - 1 && t == 0) rowptr[n] = cb + total;
}

// --------------------------- MFMA GEMM -------------------------------------
template <int COLS, bool XBF16>
__global__ __launch_bounds__(256) void k_gemm_mfma(const void* __restrict__ Xv,
                                                   const float* __restrict__ W,
                                                   ushort* __restrict__ Y, int n) {
    __shared__ ushort As[128][136];
    __shared__ ushort Ws[COLS][136];   // W^T: [col][k]
    const int t = threadIdx.x;
    const int row0 = blockIdx.x * 128;
    if constexpr (!XBF16) {
        const float* X = (const float*)Xv;
#pragma unroll
        for (int q = 0; q < 16; q++) {
            int idx = t + q * 256;
            int r = idx >> 5, c4 = (idx & 31) * 4;
            float4 xv = make_float4(0.f, 0.f, 0.f, 0.f);
            if (row0 + r < n) xv = *reinterpret_cast<const float4*>(&X[(size_t)(row0 + r) * 128 + c4]);
            ushort4 w4 = make_ushort4(f2bf(xv.x), f2bf(xv.y), f2bf(xv.z), f2bf(xv.w));
            *reinterpret_cast<ushort4*>(&As[r][c4]) = w4;
        }
    } else {
        const ushort* X = (const ushort*)Xv;
#pragma unroll
        for (int q = 0; q < 8; q++) {
            int idx = t + q * 256;
            int r = idx >> 4, c8 = (idx & 15) * 8;
            uint4 v = make_uint4(0u, 0u, 0u, 0u);
            if (row0 + r < n) v = *reinterpret_cast<const uint4*>(&X[(size_t)(row0 + r) * 128 + c8]);
            *reinterpret_cast<uint4*>(&As[r][c8]) = v;
        }
    }
    for (int i = t; i < 128 * COLS; i += 256) {
        int k = i / COLS, nc = i % COLS;
        Ws[nc][k] = f2bf(W[i]);
    }
    __syncthreads();
    const int w = t >> 6, l = t & 63;
    const int lr = l & 15;
    const int lk = (l >> 4) * 8;
    f32x4 acc[2][COLS / 16];
#pragma unroll
    for (int m = 0; m < 2; m++)
#pragma unroll
        for (int nb = 0; nb < COLS / 16; nb++) acc[m][nb] = (f32x4){0.f, 0.f, 0.f, 0.f};
#pragma unroll
    for (int kc = 0; kc < 128; kc += 32) {
        short8 a0 = *reinterpret_cast<const short8*>(&As[w * 32 + lr][kc + lk]);
        short8 a1 = *reinterpret_cast<const short8*>(&As[w * 32 + 16 + lr][kc + lk]);
#pragma unroll
        for (int nb = 0; nb < COLS / 16; nb++) {
            short8 bf = *reinterpret_cast<const short8*>(&Ws[nb * 16 + lr][kc + lk]);
            acc[0][nb] = __builtin_amdgcn_mfma_f32_16x16x32_bf16(a0, bf, acc[0][nb], 0, 0, 0);
            acc[1][nb] = __builtin_amdgcn_mfma_f32_16x16x32_bf16(a1, bf, acc[1][nb], 0, 0, 0);
        }
    }
#pragma unroll
    for (int m = 0; m < 2; m++)
#pragma unroll
        for (int j = 0; j < 4; j++) {
            int r = row0 + w * 32 + m * 16 + (l >> 4) * 4 + j;
            if (r < n) {
#pragma unroll
                for (int nb = 0; nb < COLS / 16; nb++)
                    Y[(size_t)r * COLS + nb * 16 + lr] = f2bf(acc[m][nb][j]);
            }
        }
}

// --------------------------- attention scores ------------------------------
// Written pre-scaled by log2(e): agg kernels use native exp2.
__global__ void k_attn1(const uint* __restrict__ hu, const float* __restrict__ a_src,
                        const float* __restrict__ a_dst, float* __restrict__ asrc,
                        float* __restrict__ adst, int n) {
    int t = blockIdx.x * 256 + threadIdx.x;
    if (t >= n * 8) return;
    int node = t >> 3, hd = t & 7;
    const uint* hp = hu + (size_t)node * 64 + hd * 8;
    float s1 = 0.f, s2 = 0.f;
#pragma unroll
    for (int q = 0; q < 8; q++) {
        uint u = hp[q];
        float v0 = bflo(u), v1 = bfhi(u);
        s1 = fmaf(v0, a_src[hd * 16 + 2 * q], s1);
        s1 = fmaf(v1, a_src[hd * 16 + 2 * q + 1], s1);
        s2 = fmaf(v0, a_dst[hd * 16 + 2 * q], s2);
        s2 = fmaf(v1, a_dst[hd * 16 + 2 * q + 1], s2);
    }
    asrc[t] = s1 * LOG2E;
    adst[t] = s2 * LOG2E;
}
__global__ void k_attn2(const uint* __restrict__ hu, const float* __restrict__ a_src,
                        const float* __restrict__ a_dst, float* __restrict__ asrc,
                        float* __restrict__ adst, int n) {
    int t = blockIdx.x * 256 + threadIdx.x;
    if (t >= n * 8) return;
    int node = t >> 3, j = t & 7;
    const uint* hp = hu + (size_t)node * 32 + j * 4;
    float s1 = 0.f, s2 = 0.f;
#pragma unroll
    for (int q = 0; q < 4; q++) {
        uint u = hp[q];
        float v0 = bflo(u), v1 = bfhi(u);
        s1 = fmaf(v0, a_src[j * 8 + 2 * q], s1);
        s1 = fmaf(v1, a_src[j * 8 + 2 * q + 1], s1);
        s2 = fmaf(v0, a_dst[j * 8 + 2 * q], s2);
        s2 = fmaf(v1, a_dst[j * 8 + 2 * q + 1], s2);
    }
#pragma unroll
    for (int o = 1; o < 8; o <<= 1) {
        s1 += __shfl_xor(s1, o);
        s2 += __shfl_xor(s2, o);
    }
    if (j == 0) { asrc[node] = s1 * LOG2E; adst[node] = s2 * LOG2E; }
}

// ------------------------ aggregation --------------------------------------
// conv1: one wave per dst. Per 64-slot block: (a) p-phase — lane (sl=lane&7,
// hd=lane>>3) computes p for slots {8m+sl} of head hd (zero redundancy,
// 2-way-free ds_writes into this wave's P slab), (b) s_waitcnt lgkmcnt(0),
// (c) gather loop — q via broadcast ds_read P[j*8+hd], src via readlane,
// h row via coalesced uint gather. No per-edge shfl, no streamed p.
__global__ __launch_bounds__(256) void k_agg1(
    const uint* __restrict__ hu, const float* __restrict__ asrc,
    const float* __restrict__ adst, const int* __restrict__ rowptr,
    const int* __restrict__ csr, const float* __restrict__ b1,
    uint* __restrict__ x2, int n) {
    __shared__ float P[4][512];
    int wv = threadIdx.x >> 6;
    int wid = (blockIdx.x * 256 + threadIdx.x) >> 6;
    if (wid >= n) return;
    uint lane = threadIdx.x & 63;
    uint hd = lane >> 3;
    uint sl = lane & 7;
    uint c0 = lane * 2;
    float adn = adst[(uint)wid * 8u + hd];
    int beg = rowptr[wid], end = rowptr[wid + 1];
    float s = 0.f, acc0 = 0.f, acc1 = 0.f;
    for (int base = beg; base < end; base += 64) {
        int cnt = min(64, end - base);
        int vidx = ((int)lane < cnt) ? csr[base + lane] : 0;
        // --- p-phase: all 512 (slot, head) numerators for this block ---
#pragma unroll
        for (int m = 0; m < 8; m++) {
            int slot = 8 * m + (int)sl;
            int cs = csr[base + min(slot, cnt - 1)];
            float e = asrc[(uint)cs * 8u + hd] + adn;
            e = fmaxf(e, 0.2f * e);
            P[wv][slot * 8 + hd] = exp2f(e);
        }
        asm volatile("s_waitcnt lgkmcnt(0)" ::: "memory");
        // --- gather loop ---
        int j = 0;
        for (; j + 8 <= cnt; j += 8) {
            uint s0 = __builtin_amdgcn_readlane(vidx, j);
            uint s1 = __builtin_amdgcn_readlane(vidx, j + 1);
            uint s2 = __builtin_amdgcn_readlane(vidx, j + 2);
            uint s3 = __builtin_amdgcn_readlane(vidx, j + 3);
            uint s4 = __builtin_amdgcn_readlane(vidx, j + 4);
            uint s5 = __builtin_amdgcn_readlane(vidx, j + 5);
            uint s6 = __builtin_amdgcn_readlane(vidx, j + 6);
            uint s7 = __builtin_amdgcn_readlane(vidx, j + 7);
            uint u0 = hu[s0 * 64u + lane];
            uint u1 = hu[s1 * 64u + lane];
            uint u2 = hu[s2 * 64u + lane];
            uint u3 = hu[s3 * 64u + lane];
            uint u4 = hu[s4 * 64u + lane];
            uint u5 = hu[s5 * 64u + lane];
            uint u6 = hu[s6 * 64u + lane];
            uint u7 = hu[s7 * 64u + lane];
            float q0 = P[wv][(j + 0) * 8 + hd];
            float q1 = P[wv][(j + 1) * 8 + hd];
            float q2 = P[wv][(j + 2) * 8 + hd];
            float q3 = P[wv][(j + 3) * 8 + hd];
            float q4 = P[wv][(j + 4) * 8 + hd];
            float q5 = P[wv][(j + 5) * 8 + hd];
            float q6 = P[wv][(j + 6) * 8 + hd];
            float q7 = P[wv][(j + 7) * 8 + hd];
            s += ((q0 + q1) + (q2 + q3)) + ((q4 + q5) + (q6 + q7));
            acc0 = fmaf(q0, bflo(u0), fmaf(q1, bflo(u1), acc0));
            acc0 = fmaf(q2, bflo(u2), fmaf(q3, bflo(u3), acc0));
            acc0 = fmaf(q4, bflo(u4), fmaf(q5, bflo(u5), acc0));
            acc0 = fmaf(q6, bflo(u6), fmaf(q7, bflo(u7), acc0));
            acc1 = fmaf(q0, bfhi(u0), fmaf(q1, bfhi(u1), acc1));
            acc1 = fmaf(q2, bfhi(u2), fmaf(q3, bfhi(u3), acc1));
            acc1 = fmaf(q4, bfhi(u4), fmaf(q5, bfhi(u5), acc1));
            acc1 = fmaf(q6, bfhi(u6), fmaf(q7, bfhi(u7), acc1));
        }
        for (; j < cnt; ++j) {
            uint s0 = __builtin_amdgcn_readlane(vidx, j);
            float q0 = P[wv][j * 8 + hd];
            uint u0 = hu[s0 * 64u + lane];
            s += q0;
            acc0 = fmaf(q0, bflo(u0), acc0);
            acc1 = fmaf(q0, bfhi(u0), acc1);
        }
    }
    float inv = 1.f / (s + 1e-16f);
    float o0 = acc0 * inv + b1[c0];
    float o1 = acc1 * inv + b1[c0 + 1];
    o0 = o0 > 0.f ? o0 : (__expf(o0) - 1.f);  // ELU
    o1 = o1 > 0.f ? o1 : (__expf(o1) - 1.f);
    union { ushort b[2]; uint u; } pk;
    pk.b[0] = f2bf(o0);
    pk.b[1] = f2bf(o1);
    x2[(uint)wid * 64u + lane] = pk.u;
}
// conv2: single head — lane computes p for its own slot (from vidx, no extra
// loads), broadcast ds_read in the gather loop.
__global__ __launch_bounds__(256) void k_agg2(
    const ushort* __restrict__ hb, const float* __restrict__ asrc,
    const float* __restrict__ adst, const int* __restrict__ rowptr,
    const int* __restrict__ csr, const float* __restrict__ b2,
    float* __restrict__ out, int n) {
    __shared__ float P2[4][64];
    int wv = threadIdx.x >> 6;
    int wid = (blockIdx.x * 256 + threadIdx.x) >> 6;
    if (wid >= n) return;
    uint lane = threadIdx.x & 63;
    float adn = adst[wid];
    int beg = rowptr[wid], end = rowptr[wid + 1];
    float s = 0.f, acc = 0.f;
    for (int base = beg; base < end; base += 64) {
        int cnt = min(64, end - base);
        int vidx = csr[base + min((int)lane, cnt - 1)];
        // --- p-phase ---
        float e = asrc[vidx] + adn;
        e = fmaxf(e, 0.2f * e);
        P2[wv][lane] = ((int)lane < cnt) ? exp2f(e) : 0.f;
        asm volatile("s_waitcnt lgkmcnt(0)" ::: "memory");
        // --- gather loop ---
        int j = 0;
        for (; j + 8 <= cnt; j += 8) {
            uint s0 = __builtin_amdgcn_readlane(vidx, j);
            uint s1 = __builtin_amdgcn_readlane(vidx, j + 1);
            uint s2 = __builtin_amdgcn_readlane(vidx, j + 2);
            uint s3 = __builtin_amdgcn_readlane(vidx, j + 3);
            uint s4 = __builtin_amdgcn_readlane(vidx, j + 4);
            uint s5 = __builtin_amdgcn_readlane(vidx, j + 5);
            uint s6 = __builtin_amdgcn_readlane(vidx, j + 6);
            uint s7 = __builtin_amdgcn_readlane(vidx, j + 7);
            float h0 = bf1(hb[s0 * 64u + lane]);
            float h1 = bf1(hb[s1 * 64u + lane]);
            float h2 = bf1(hb[s2 * 64u + lane]);
            float h3 = bf1(hb[s3 * 64u + lane]);
            float h4 = bf1(hb[s4 * 64u + lane]);
            float h5 = bf1(hb[s5 * 64u + lane]);
            float h6 = bf1(hb[s6 * 64u + lane]);
            float h7 = bf1(hb[s7 * 64u + lane]);
            float q0 = P2[wv][j + 0];
            float q1 = P2[wv][j + 1];
            float q2 = P2[wv][j + 2];
            float q3 = P2[wv][j + 3];
            float q4 = P2[wv][j + 4];
            float q5 = P2[wv][j + 5];
            float q6 = P2[wv][j + 6];
            float q7 = P2[wv][j + 7];
            s += ((q0 + q1) + (q2 + q3)) + ((q4 + q5) + (q6 + q7));
            acc = fmaf(q0, h0, fmaf(q1, h1, acc));
            acc = fmaf(q2, h2, fmaf(q3, h3, acc));
            acc = fmaf(q4, h4, fmaf(q5, h5, acc));
            acc = fmaf(q6, h6, fmaf(q7, h7, acc));
        }
        for (; j < cnt; ++j) {
            uint s0 = __builtin_amdgcn_readlane(vidx, j);
            float q0 = P2[wv][j];
            float h0 = bf1(hb[s0 * 64u + lane]);
            s += q0;
            acc = fmaf(q0, h0, acc);
        }
    }
    out[(size_t)wid * 64 + lane] = acc / (s + 1e-16f) + b2[lane];
}

// ------------------------------- launch -------------------------------------
extern "C" void kernel_launch(void* const* d_in, const int* in_sizes, int n_in,
                              void* d_out, int out_size, void* d_ws, size_t ws_size,
                              hipStream_t stream) {
    const float* x   = (const float*)d_in[0];
    const int*   ei  = (const int*)d_in[1];
    const float* W1  = (const float*)d_in[2];
    const float* as1 = (const float*)d_in[3];
    const float* ad1 = (const float*)d_in[4];
    const float* b1  = (const float*)d_in[5];
    const float* W2  = (const float*)d_in[6];
    const float* as2 = (const float*)d_in[7];
    const float* ad2 = (const float*)d_in[8];
    const float* b2  = (const float*)d_in[9];
    float* out = (float*)d_out;

    int N = in_sizes[0] / 128;
    int E = in_sizes[1] / 2;
    int TOT = E + N;
    const int* src = ei;
    const int* dst = ei + E;

    char* p = (char*)d_ws;
    auto alloc = [&](size_t bytes) {
        char* r = p;
        p += (bytes + 255) & ~size_t(255);
        return r;
    };
    ushort* h1b  = (ushort*)alloc((size_t)N * 128 * 2);
    ushort* h2b  = (ushort*)alloc((size_t)N * 64 * 2);
    ushort* x2b  = (ushort*)alloc((size_t)N * 128 * 2);
    float* asrc1 = (float*)alloc((size_t)N * 8 * 4);
    float* adst1 = (float*)alloc((size_t)N * 8 * 4);
    float* asrc2 = (float*)alloc((size_t)N * 4);
    float* adst2 = (float*)alloc((size_t)N * 4);
    int* rowptr  = (int*)alloc((size_t)(N + 1) * 4);
    int* csr     = (int*)alloc((size_t)TOT * 4);
    int* ebuf    = (int*)alloc((size_t)E * 4);
    int* bcount  = (int*)alloc(1024 * 4);
    int* ebase   = (int*)alloc(1024 * 4);
    int* ecur    = (int*)alloc(1024 * 4);
    int* cbase   = (int*)alloc(1024 * 4);

    int NB = (N + 127) >> 7;
    int nbp = (E + 8191) / 8192;

    // CSR build
    hipMemsetAsync(bcount, 0, 1024 * 4, stream);
    k_bhist<<<nbp, 512, 0, stream>>>(dst, E, bcount);
    k_bscan<<<1, 256, 0, stream>>>(bcount, NB, N, ebase, ecur, cbase);
    k_part<<<nbp, 512, 0, stream>>>(src, dst, E, ecur, ebuf);
    k_build<<<NB, 256, 0, stream>>>(ebuf, bcount, ebase, cbase, rowptr, csr, N, NB);

    int gb = (N + 127) / 128;
    // conv1
    k_gemm_mfma<128, false><<<gb, 256, 0, stream>>>(x, W1, h1b, N);
    k_attn1<<<(N * 8 + 255) / 256, 256, 0, stream>>>((const uint*)h1b, as1, ad1, asrc1, adst1, N);
    k_agg1<<<(N + 3) / 4, 256, 0, stream>>>((const uint*)h1b, asrc1, adst1, rowptr, csr, b1,
                                            (uint*)x2b, N);

    // conv2
    k_gemm_mfma<64, true><<<gb, 256, 0, stream>>>(x2b, W2, h2b, N);
    k_attn2<<<(N * 8 + 255) / 256, 256, 0, stream>>>((const uint*)h2b, as2, ad2, asrc2, adst2, N);
    k_agg2<<<(N + 3) / 4, 256, 0, stream>>>((const ushort*)h2b, asrc2, adst2, rowptr, csr, b2,
                                            out, N);
}

// Round 11
// 235.830 us; speedup vs baseline: 1.3168x; 1.0261x over previous
//
#include <hip/hip_runtime.h>
#include <hip/hip_bf16.h>
#include <math.h>

// ---------------------------------------------------------------------------
// 2-layer GAT on MI355X.
// R11: (a) agg1 p-phase bounded by cnt (R10 ran fixed 64 slots vs mean deg
// ~18 -> ~147MB wasted asrc fetches); (b) independent dispatch chains fused
// by block-role split: {bhist || gemm1}, {bscan || attn1}. Rest = R10.
// ---------------------------------------------------------------------------

typedef __attribute__((ext_vector_type(8))) short short8;
typedef __attribute__((ext_vector_type(4))) float f32x4;

__device__ __forceinline__ float bflo(uint u) { return __uint_as_float(u << 16); }
__device__ __forceinline__ float bfhi(uint u) { return __uint_as_float(u & 0xffff0000u); }
__device__ __forceinline__ float bf1(ushort v) { return __uint_as_float(((uint)v) << 16); }
__device__ __forceinline__ ushort f2bf(float f) {  // RNE f32->bf16
    uint u = __float_as_uint(f);
    u += 0x7fff + ((u >> 16) & 1);
    return (ushort)(u >> 16);
}
#define LOG2E 1.44269504088896f
#define CSR_CAP 4096

// ---------------- K_A: fused bucket-histogram + conv1 GEMM -----------------
// blocks [0, nbh): histogram dst into 1024 buckets of 128 nodes.
// blocks [nbh, nbh+gb): Y[n,128](bf16) = X[n,128](f32) @ W1[128,128], MFMA.
__global__ __launch_bounds__(256) void k_gemm1_bhist(
    const float* __restrict__ X, const float* __restrict__ W,
    ushort* __restrict__ Y, int n,
    const int* __restrict__ dst, int e, int* __restrict__ bcount, int nbh) {
    __shared__ union {
        struct { ushort As[128][136]; ushort Ws[128][136]; } g;
        int h[1024];
    } sm;
    const int t = threadIdx.x;
    if ((int)blockIdx.x < nbh) {
        // ---- histogram role ----
        for (int i = t; i < 1024; i += 256) sm.h[i] = 0;
        __syncthreads();
        int c0 = blockIdx.x * 8192, c1 = min(c0 + 8192, e);
        for (int i = c0 + t; i < c1; i += 256) atomicAdd(&sm.h[dst[i] >> 7], 1);
        __syncthreads();
        for (int i = t; i < 1024; i += 256)
            if (sm.h[i]) atomicAdd(&bcount[i], sm.h[i]);
        return;
    }
    // ---- GEMM role ----
    const int row0 = (blockIdx.x - nbh) * 128;
#pragma unroll
    for (int q = 0; q < 16; q++) {
        int idx = t + q * 256;
        int r = idx >> 5, c4 = (idx & 31) * 4;
        float4 xv = make_float4(0.f, 0.f, 0.f, 0.f);
        if (row0 + r < n) xv = *reinterpret_cast<const float4*>(&X[(size_t)(row0 + r) * 128 + c4]);
        ushort4 w4 = make_ushort4(f2bf(xv.x), f2bf(xv.y), f2bf(xv.z), f2bf(xv.w));
        *reinterpret_cast<ushort4*>(&sm.g.As[r][c4]) = w4;
    }
    for (int i = t; i < 128 * 128; i += 256) {
        int k = i >> 7, nc = i & 127;
        sm.g.Ws[nc][k] = f2bf(W[i]);
    }
    __syncthreads();
    const int w = t >> 6, l = t & 63;
    const int lr = l & 15;
    const int lk = (l >> 4) * 8;
    f32x4 acc[2][8];
#pragma unroll
    for (int m = 0; m < 2; m++)
#pragma unroll
        for (int nb = 0; nb < 8; nb++) acc[m][nb] = (f32x4){0.f, 0.f, 0.f, 0.f};
#pragma unroll
    for (int kc = 0; kc < 128; kc += 32) {
        short8 a0 = *reinterpret_cast<const short8*>(&sm.g.As[w * 32 + lr][kc + lk]);
        short8 a1 = *reinterpret_cast<const short8*>(&sm.g.As[w * 32 + 16 + lr][kc + lk]);
#pragma unroll
        for (int nb = 0; nb < 8; nb++) {
            short8 bf = *reinterpret_cast<const short8*>(&sm.g.Ws[nb * 16 + lr][kc + lk]);
            acc[0][nb] = __builtin_amdgcn_mfma_f32_16x16x32_bf16(a0, bf, acc[0][nb], 0, 0, 0);
            acc[1][nb] = __builtin_amdgcn_mfma_f32_16x16x32_bf16(a1, bf, acc[1][nb], 0, 0, 0);
        }
    }
#pragma unroll
    for (int m = 0; m < 2; m++)
#pragma unroll
        for (int j = 0; j < 4; j++) {
            int r = row0 + w * 32 + m * 16 + (l >> 4) * 4 + j;
            if (r < n) {
#pragma unroll
                for (int nb = 0; nb < 8; nb++)
                    Y[(size_t)r * 128 + nb * 16 + lr] = f2bf(acc[m][nb][j]);
            }
        }
}

// ---------------- K_B: fused bucket-scan + conv1 attention -----------------
// block 0: exclusive scans over bucket sizes. blocks >0: attn1.
__global__ __launch_bounds__(256) void k_bscan_attn1(
    const int* __restrict__ bcount, int nb, int n,
    int* __restrict__ ebase, int* __restrict__ ecur, int* __restrict__ cbase,
    const uint* __restrict__ hu, const float* __restrict__ a_src,
    const float* __restrict__ a_dst, float* __restrict__ asrc,
    float* __restrict__ adst) {
    __shared__ int ae[1024], be[1024], ac[1024], bc[1024];
    int t = threadIdx.x;
    if (blockIdx.x == 0) {
        for (int i = t; i < 1024; i += 256) {
            int v = 0, nn = 0;
            if (i < nb) {
                v = bcount[i];
                nn = min(128, n - (i << 7));
            }
            ae[i] = v;
            ac[i] = v + nn;
        }
        __syncthreads();
        int* pa = ae; int* qa = be; int* pc = ac; int* qc = bc;
        for (int off = 1; off < 1024; off <<= 1) {
            for (int i = t; i < 1024; i += 256) {
                int va = pa[i], vc = pc[i];
                if (i >= off) { va += pa[i - off]; vc += pc[i - off]; }
                qa[i] = va; qc[i] = vc;
            }
            __syncthreads();
            int* tm = pa; pa = qa; qa = tm;
            tm = pc; pc = qc; qc = tm;
        }
        for (int i = t; i < 1024; i += 256) {
            if (i < nb) {
                int ea = (i == 0) ? 0 : pa[i - 1];
                int ca = (i == 0) ? 0 : pc[i - 1];
                ebase[i] = ea; ecur[i] = ea; cbase[i] = ca;
            }
        }
        return;
    }
    int tt = (blockIdx.x - 1) * 256 + t;
    if (tt >= n * 8) return;
    int node = tt >> 3, hd = tt & 7;
    const uint* hp = hu + (size_t)node * 64 + hd * 8;
    float s1 = 0.f, s2 = 0.f;
#pragma unroll
    for (int q = 0; q < 8; q++) {
        uint u = hp[q];
        float v0 = bflo(u), v1 = bfhi(u);
        s1 = fmaf(v0, a_src[hd * 16 + 2 * q], s1);
        s1 = fmaf(v1, a_src[hd * 16 + 2 * q + 1], s1);
        s2 = fmaf(v0, a_dst[hd * 16 + 2 * q], s2);
        s2 = fmaf(v1, a_dst[hd * 16 + 2 * q + 1], s2);
    }
    asrc[tt] = s1 * LOG2E;
    adst[tt] = s2 * LOG2E;
}

// ---------------- partition + build (unchanged from R10) -------------------
__global__ __launch_bounds__(512) void k_part(const int* __restrict__ src,
                                              const int* __restrict__ dst, int e,
                                              int* __restrict__ ecur, int* __restrict__ ebuf) {
    __shared__ int h[1024];
    __shared__ int base[1024];
    int t = threadIdx.x;
    int c0 = blockIdx.x * 8192, c1 = min(c0 + 8192, e);
    for (int i = t; i < 1024; i += 512) h[i] = 0;
    __syncthreads();
    for (int i = c0 + t; i < c1; i += 512) atomicAdd(&h[dst[i] >> 7], 1);
    __syncthreads();
    for (int i = t; i < 1024; i += 512) {
        int c = h[i];
        base[i] = c ? atomicAdd(&ecur[i], c) : 0;
        h[i] = 0;
    }
    __syncthreads();
    for (int i = c0 + t; i < c1; i += 512) {
        int d = dst[i], b = d >> 7;
        int r = atomicAdd(&h[b], 1);
        ebuf[base[b] + r] = (src[i] << 7) | (d & 127);
    }
}

__global__ __launch_bounds__(256) void k_build(const int* __restrict__ ebuf,
                                               const int* __restrict__ bcount,
                                               const int* __restrict__ ebase,
                                               const int* __restrict__ cbase,
                                               int* __restrict__ rowptr,
                                               int* __restrict__ csr, int n, int nb) {
    __shared__ int cnt[128];
    __shared__ int sc[128], sc2[128];
    __shared__ int csr_l[CSR_CAP];
    int b = blockIdx.x, t = threadIdx.x;
    int n0 = b << 7;
    int nn = min(128, n - n0);
    int ec = bcount[b], eb = ebase[b], cb = cbase[b];
    if (t < 128) cnt[t] = 0;
    __syncthreads();
    for (int i = t; i < ec; i += 256) atomicAdd(&cnt[ebuf[eb + i] & 127], 1);
    __syncthreads();
    if (t < 128) sc[t] = (t < nn) ? cnt[t] + 1 : 0;
    __syncthreads();
    int* p = sc; int* q = sc2;
    for (int off = 1; off < 128; off <<= 1) {
        if (t < 128) {
            int v = p[t];
            if (t >= off) v += p[t - off];
            q[t] = v;
        }
        __syncthreads();
        int* tm = p; p = q; q = tm;
    }
    int total = p[127];  // == ec + nn
    if (total <= CSR_CAP) {
        if (t < nn) {
            int off = (t == 0) ? 0 : p[t - 1];
            rowptr[n0 + t] = cb + off;
            csr_l[off] = n0 + t;   // self-loop
            cnt[t] = off + 1;
        }
        __syncthreads();
        for (int i = t; i < ec; i += 256) {
            int v = ebuf[eb + i];
            int s = atomicAdd(&cnt[v & 127], 1);
            csr_l[s] = v >> 7;
        }
        __syncthreads();
        for (int i = t; i < total; i += 256) csr[cb + i] = csr_l[i];
    } else {  // fallback (never taken for random graphs)
        if (t < nn) {
            int off = (t == 0) ? 0 : p[t - 1];
            rowptr[n0 + t] = cb + off;
            csr[cb + off] = n0 + t;
            cnt[t] = off + 1;
        }
        __syncthreads();
        for (int i = t; i < ec; i += 256) {
            int v = ebuf[eb + i];
            int s = atomicAdd(&cnt[v & 127], 1);
            csr[cb + s] = v >> 7;
        }
    }
    if (b == nb - 1 && t == 0) rowptr[n] = cb + total;
}

// ---------------- conv2 GEMM (bf16 in) + attn2 (unchanged) -----------------
__global__ __launch_bounds__(256) void k_gemm2(const ushort* __restrict__ X,
                                               const float* __restrict__ W,
                                               ushort* __restrict__ Y, int n) {
    __shared__ ushort As[128][136];
    __shared__ ushort Ws[64][136];
    const int t = threadIdx.x;
    const int row0 = blockIdx.x * 128;
#pragma unroll
    for (int q = 0; q < 8; q++) {
        int idx = t + q * 256;
        int r = idx >> 4, c8 = (idx & 15) * 8;
        uint4 v = make_uint4(0u, 0u, 0u, 0u);
        if (row0 + r < n) v = *reinterpret_cast<const uint4*>(&X[(size_t)(row0 + r) * 128 + c8]);
        *reinterpret_cast<uint4*>(&As[r][c8]) = v;
    }
    for (int i = t; i < 128 * 64; i += 256) {
        int k = i >> 6, nc = i & 63;
        Ws[nc][k] = f2bf(W[i]);
    }
    __syncthreads();
    const int w = t >> 6, l = t & 63;
    const int lr = l & 15;
    const int lk = (l >> 4) * 8;
    f32x4 acc[2][4];
#pragma unroll
    for (int m = 0; m < 2; m++)
#pragma unroll
        for (int nb = 0; nb < 4; nb++) acc[m][nb] = (f32x4){0.f, 0.f, 0.f, 0.f};
#pragma unroll
    for (int kc = 0; kc < 128; kc += 32) {
        short8 a0 = *reinterpret_cast<const short8*>(&As[w * 32 + lr][kc + lk]);
        short8 a1 = *reinterpret_cast<const short8*>(&As[w * 32 + 16 + lr][kc + lk]);
#pragma unroll
        for (int nb = 0; nb < 4; nb++) {
            short8 bf = *reinterpret_cast<const short8*>(&Ws[nb * 16 + lr][kc + lk]);
            acc[0][nb] = __builtin_amdgcn_mfma_f32_16x16x32_bf16(a0, bf, acc[0][nb], 0, 0, 0);
            acc[1][nb] = __builtin_amdgcn_mfma_f32_16x16x32_bf16(a1, bf, acc[1][nb], 0, 0, 0);
        }
    }
#pragma unroll
    for (int m = 0; m < 2; m++)
#pragma unroll
        for (int j = 0; j < 4; j++) {
            int r = row0 + w * 32 + m * 16 + (l >> 4) * 4 + j;
            if (r < n) {
#pragma unroll
                for (int nb = 0; nb < 4; nb++)
                    Y[(size_t)r * 64 + nb * 16 + lr] = f2bf(acc[m][nb][j]);
            }
        }
}

__global__ void k_attn2(const uint* __restrict__ hu, const float* __restrict__ a_src,
                        const float* __restrict__ a_dst, float* __restrict__ asrc,
                        float* __restrict__ adst, int n) {
    int t = blockIdx.x * 256 + threadIdx.x;
    if (t >= n * 8) return;
    int node = t >> 3, j = t & 7;
    const uint* hp = hu + (size_t)node * 32 + j * 4;
    float s1 = 0.f, s2 = 0.f;
#pragma unroll
    for (int q = 0; q < 4; q++) {
        uint u = hp[q];
        float v0 = bflo(u), v1 = bfhi(u);
        s1 = fmaf(v0, a_src[j * 8 + 2 * q], s1);
        s1 = fmaf(v1, a_src[j * 8 + 2 * q + 1], s1);
        s2 = fmaf(v0, a_dst[j * 8 + 2 * q], s2);
        s2 = fmaf(v1, a_dst[j * 8 + 2 * q + 1], s2);
    }
#pragma unroll
    for (int o = 1; o < 8; o <<= 1) {
        s1 += __shfl_xor(s1, o);
        s2 += __shfl_xor(s2, o);
    }
    if (j == 0) { asrc[node] = s1 * LOG2E; adst[node] = s2 * LOG2E; }
}

// ------------------------ aggregation --------------------------------------
// conv1: one wave per dst. Per 64-slot block: p-phase bounded by cnt
// (ceil(cnt/8) iterations; R10 ran all 8) -> lgkmcnt(0) -> gather loop.
__global__ __launch_bounds__(256) void k_agg1(
    const uint* __restrict__ hu, const float* __restrict__ asrc,
    const float* __restrict__ adst, const int* __restrict__ rowptr,
    const int* __restrict__ csr, const float* __restrict__ b1,
    uint* __restrict__ x2, int n) {
    __shared__ float P[4][512];
    int wv = threadIdx.x >> 6;
    int wid = (blockIdx.x * 256 + threadIdx.x) >> 6;
    if (wid >= n) return;
    uint lane = threadIdx.x & 63;
    uint hd = lane >> 3;
    uint sl = lane & 7;
    uint c0 = lane * 2;
    float adn = adst[(uint)wid * 8u + hd];
    int beg = rowptr[wid], end = rowptr[wid + 1];
    float s = 0.f, acc0 = 0.f, acc1 = 0.f;
    for (int base = beg; base < end; base += 64) {
        int cnt = min(64, end - base);
        int vidx = ((int)lane < cnt) ? csr[base + lane] : 0;
        // --- p-phase: only ceil(cnt/8) slot groups ---
        int mb = (cnt + 7) >> 3;
        for (int m = 0; m < mb; m++) {
            int slot = 8 * m + (int)sl;
            int cs = csr[base + min(slot, cnt - 1)];
            float e = asrc[(uint)cs * 8u + hd] + adn;
            e = fmaxf(e, 0.2f * e);
            P[wv][slot * 8 + hd] = exp2f(e);
        }
        asm volatile("s_waitcnt lgkmcnt(0)" ::: "memory");
        // --- gather loop ---
        int j = 0;
        for (; j + 8 <= cnt; j += 8) {
            uint s0 = __builtin_amdgcn_readlane(vidx, j);
            uint s1 = __builtin_amdgcn_readlane(vidx, j + 1);
            uint s2 = __builtin_amdgcn_readlane(vidx, j + 2);
            uint s3 = __builtin_amdgcn_readlane(vidx, j + 3);
            uint s4 = __builtin_amdgcn_readlane(vidx, j + 4);
            uint s5 = __builtin_amdgcn_readlane(vidx, j + 5);
            uint s6 = __builtin_amdgcn_readlane(vidx, j + 6);
            uint s7 = __builtin_amdgcn_readlane(vidx, j + 7);
            uint u0 = hu[s0 * 64u + lane];
            uint u1 = hu[s1 * 64u + lane];
            uint u2 = hu[s2 * 64u + lane];
            uint u3 = hu[s3 * 64u + lane];
            uint u4 = hu[s4 * 64u + lane];
            uint u5 = hu[s5 * 64u + lane];
            uint u6 = hu[s6 * 64u + lane];
            uint u7 = hu[s7 * 64u + lane];
            float q0 = P[wv][(j + 0) * 8 + hd];
            float q1 = P[wv][(j + 1) * 8 + hd];
            float q2 = P[wv][(j + 2) * 8 + hd];
            float q3 = P[wv][(j + 3) * 8 + hd];
            float q4 = P[wv][(j + 4) * 8 + hd];
            float q5 = P[wv][(j + 5) * 8 + hd];
            float q6 = P[wv][(j + 6) * 8 + hd];
            float q7 = P[wv][(j + 7) * 8 + hd];
            s += ((q0 + q1) + (q2 + q3)) + ((q4 + q5) + (q6 + q7));
            acc0 = fmaf(q0, bflo(u0), fmaf(q1, bflo(u1), acc0));
            acc0 = fmaf(q2, bflo(u2), fmaf(q3, bflo(u3), acc0));
            acc0 = fmaf(q4, bflo(u4), fmaf(q5, bflo(u5), acc0));
            acc0 = fmaf(q6, bflo(u6), fmaf(q7, bflo(u7), acc0));
            acc1 = fmaf(q0, bfhi(u0), fmaf(q1, bfhi(u1), acc1));
            acc1 = fmaf(q2, bfhi(u2), fmaf(q3, bfhi(u3), acc1));
            acc1 = fmaf(q4, bfhi(u4), fmaf(q5, bfhi(u5), acc1));
            acc1 = fmaf(q6, bfhi(u6), fmaf(q7, bfhi(u7), acc1));
        }
        for (; j < cnt; ++j) {
            uint s0 = __builtin_amdgcn_readlane(vidx, j);
            float q0 = P[wv][j * 8 + hd];
            uint u0 = hu[s0 * 64u + lane];
            s += q0;
            acc0 = fmaf(q0, bflo(u0), acc0);
            acc1 = fmaf(q0, bfhi(u0), acc1);
        }
    }
    float inv = 1.f / (s + 1e-16f);
    float o0 = acc0 * inv + b1[c0];
    float o1 = acc1 * inv + b1[c0 + 1];
    o0 = o0 > 0.f ? o0 : (__expf(o0) - 1.f);  // ELU
    o1 = o1 > 0.f ? o1 : (__expf(o1) - 1.f);
    union { ushort b[2]; uint u; } pk;
    pk.b[0] = f2bf(o0);
    pk.b[1] = f2bf(o1);
    x2[(uint)wid * 64u + lane] = pk.u;
}
// conv2: single head — lane computes p for its own slot; broadcast ds_read.
__global__ __launch_bounds__(256) void k_agg2(
    const ushort* __restrict__ hb, const float* __restrict__ asrc,
    const float* __restrict__ adst, const int* __restrict__ rowptr,
    const int* __restrict__ csr, const float* __restrict__ b2,
    float* __restrict__ out, int n) {
    __shared__ float P2[4][64];
    int wv = threadIdx.x >> 6;
    int wid = (blockIdx.x * 256 + threadIdx.x) >> 6;
    if (wid >= n) return;
    uint lane = threadIdx.x & 63;
    float adn = adst[wid];
    int beg = rowptr[wid], end = rowptr[wid + 1];
    float s = 0.f, acc = 0.f;
    for (int base = beg; base < end; base += 64) {
        int cnt = min(64, end - base);
        int vidx = csr[base + min((int)lane, cnt - 1)];
        float e = asrc[vidx] + adn;
        e = fmaxf(e, 0.2f * e);
        P2[wv][lane] = ((int)lane < cnt) ? exp2f(e) : 0.f;
        asm volatile("s_waitcnt lgkmcnt(0)" ::: "memory");
        int j = 0;
        for (; j + 8 <= cnt; j += 8) {
            uint s0 = __builtin_amdgcn_readlane(vidx, j);
            uint s1 = __builtin_amdgcn_readlane(vidx, j + 1);
            uint s2 = __builtin_amdgcn_readlane(vidx, j + 2);
            uint s3 = __builtin_amdgcn_readlane(vidx, j + 3);
            uint s4 = __builtin_amdgcn_readlane(vidx, j + 4);
            uint s5 = __builtin_amdgcn_readlane(vidx, j + 5);
            uint s6 = __builtin_amdgcn_readlane(vidx, j + 6);
            uint s7 = __builtin_amdgcn_readlane(vidx, j + 7);
            float h0 = bf1(hb[s0 * 64u + lane]);
            float h1 = bf1(hb[s1 * 64u + lane]);
            float h2 = bf1(hb[s2 * 64u + lane]);
            float h3 = bf1(hb[s3 * 64u + lane]);
            float h4 = bf1(hb[s4 * 64u + lane]);
            float h5 = bf1(hb[s5 * 64u + lane]);
            float h6 = bf1(hb[s6 * 64u + lane]);
            float h7 = bf1(hb[s7 * 64u + lane]);
            float q0 = P2[wv][j + 0];
            float q1 = P2[wv][j + 1];
            float q2 = P2[wv][j + 2];
            float q3 = P2[wv][j + 3];
            float q4 = P2[wv][j + 4];
            float q5 = P2[wv][j + 5];
            float q6 = P2[wv][j + 6];
            float q7 = P2[wv][j + 7];
            s += ((q0 + q1) + (q2 + q3)) + ((q4 + q5) + (q6 + q7));
            acc = fmaf(q0, h0, fmaf(q1, h1, acc));
            acc = fmaf(q2, h2, fmaf(q3, h3, acc));
            acc = fmaf(q4, h4, fmaf(q5, h5, acc));
            acc = fmaf(q6, h6, fmaf(q7, h7, acc));
        }
        for (; j < cnt; ++j) {
            uint s0 = __builtin_amdgcn_readlane(vidx, j);
            float q0 = P2[wv][j];
            float h0 = bf1(hb[s0 * 64u + lane]);
            s += q0;
            acc = fmaf(q0, h0, acc);
        }
    }
    out[(size_t)wid * 64 + lane] = acc / (s + 1e-16f) + b2[lane];
}

// ------------------------------- launch -------------------------------------
extern "C" void kernel_launch(void* const* d_in, const int* in_sizes, int n_in,
                              void* d_out, int out_size, void* d_ws, size_t ws_size,
                              hipStream_t stream) {
    const float* x   = (const float*)d_in[0];
    const int*   ei  = (const int*)d_in[1];
    const float* W1  = (const float*)d_in[2];
    const float* as1 = (const float*)d_in[3];
    const float* ad1 = (const float*)d_in[4];
    const float* b1  = (const float*)d_in[5];
    const float* W2  = (const float*)d_in[6];
    const float* as2 = (const float*)d_in[7];
    const float* ad2 = (const float*)d_in[8];
    const float* b2  = (const float*)d_in[9];
    float* out = (float*)d_out;

    int N = in_sizes[0] / 128;
    int E = in_sizes[1] / 2;
    int TOT = E + N;
    const int* src = ei;
    const int* dst = ei + E;

    char* p = (char*)d_ws;
    auto alloc = [&](size_t bytes) {
        char* r = p;
        p += (bytes + 255) & ~size_t(255);
        return r;
    };
    ushort* h1b  = (ushort*)alloc((size_t)N * 128 * 2);
    ushort* h2b  = (ushort*)alloc((size_t)N * 64 * 2);
    ushort* x2b  = (ushort*)alloc((size_t)N * 128 * 2);
    float* asrc1 = (float*)alloc((size_t)N * 8 * 4);
    float* adst1 = (float*)alloc((size_t)N * 8 * 4);
    float* asrc2 = (float*)alloc((size_t)N * 4);
    float* adst2 = (float*)alloc((size_t)N * 4);
    int* rowptr  = (int*)alloc((size_t)(N + 1) * 4);
    int* csr     = (int*)alloc((size_t)TOT * 4);
    int* ebuf    = (int*)alloc((size_t)E * 4);
    int* bcount  = (int*)alloc(1024 * 4);
    int* ebase   = (int*)alloc(1024 * 4);
    int* ecur    = (int*)alloc(1024 * 4);
    int* cbase   = (int*)alloc(1024 * 4);

    int NB = (N + 127) >> 7;
    int nbp = (E + 8191) / 8192;
    int gb = (N + 127) / 128;

    hipMemsetAsync(bcount, 0, 1024 * 4, stream);
    // K_A: bhist || gemm1
    k_gemm1_bhist<<<nbp + gb, 256, 0, stream>>>(x, W1, h1b, N, dst, E, bcount, nbp);
    // K_B: bscan || attn1
    k_bscan_attn1<<<1 + (N * 8 + 255) / 256, 256, 0, stream>>>(
        bcount, NB, N, ebase, ecur, cbase, (const uint*)h1b, as1, ad1, asrc1, adst1);
    k_part<<<nbp, 512, 0, stream>>>(src, dst, E, ecur, ebuf);
    k_build<<<NB, 256, 0, stream>>>(ebuf, bcount, ebase, cbase, rowptr, csr, N, NB);
    k_agg1<<<(N + 3) / 4, 256, 0, stream>>>((const uint*)h1b, asrc1, adst1, rowptr, csr, b1,
                                            (uint*)x2b, N);
    // conv2
    k_gemm2<<<gb, 256, 0, stream>>>(x2b, W2, h2b, N);
    k_attn2<<<(N * 8 + 255) / 256, 256, 0, stream>>>((const uint*)h2b, as2, ad2, asrc2, adst2, N);
    k_agg2<<<(N + 3) / 4, 256, 0, stream>>>((const ushort*)h2b, asrc2, adst2, rowptr, csr, b2,
                                            out, N);
}